// Round 2
// baseline (2039.204 us; speedup 1.0000x reference)
//
#include <hip/hip_runtime.h>
#include <math.h>

#define B_ 8
#define N_ 1024
#define D_ 512
#define CH 16
#define CHUNK (N_/CH)   /* 64 rows per column-chunk */
#define EPSF 1e-8f

// ---------------- reduction helpers (256-thread blocks = 4 waves) ----------------
static __device__ __forceinline__ float wredMax(float v){
#pragma unroll
  for (int o=32;o>=1;o>>=1) v = fmaxf(v, __shfl_xor(v,o,64));
  return v;
}
static __device__ __forceinline__ float wredSum(float v){
#pragma unroll
  for (int o=32;o>=1;o>>=1) v += __shfl_xor(v,o,64);
  return v;
}
static __device__ __forceinline__ float blockMax(float v, float* sm){
  v = wredMax(v);
  int w = threadIdx.x>>6, l = threadIdx.x&63;
  if (l==0) sm[w]=v;
  __syncthreads();
  float r = fmaxf(fmaxf(sm[0],sm[1]),fmaxf(sm[2],sm[3]));
  __syncthreads();
  return r;
}
static __device__ __forceinline__ float blockSum(float v, float* sm){
  v = wredSum(v);
  int w = threadIdx.x>>6, l = threadIdx.x&63;
  if (l==0) sm[w]=v;
  __syncthreads();
  float r = (sm[0]+sm[1])+(sm[2]+sm[3]);
  __syncthreads();
  return r;
}

// ---------------- init: materialize all state as (B,N,D) ----------------
__global__ __launch_bounds__(256)
void init_kernel(float* __restrict__ logT, float* __restrict__ logS,
                 float* __restrict__ Z, float* __restrict__ logMu,
                 float* __restrict__ logEta, float* __restrict__ Z1,
                 float* __restrict__ Z2,
                 const float* __restrict__ p0, const float* __restrict__ q0)
{
  long i = (long)blockIdx.x*256 + threadIdx.x;
  int d  = (int)(i & (D_-1));
  long bn = i >> 9;               // i / D_
  int b  = (int)(bn >> 10);       // bn / N_
  float p = p0[b*D_ + d];
  float q = q0[bn];
  float lt = logf(q*p + EPSF);
  logT[i] = lt;
  logS[i] = lt;
  Z[i] = 0.f;
  logMu[i]  = logf(p);
  logEta[i] = logf(q + EPSF);
  Z1[i] = 0.f;
  Z2[i] = 0.f;
}

__global__ __launch_bounds__(256)
void exp_kernel(const float* __restrict__ in, float* __restrict__ out)
{
  long i = (long)blockIdx.x*256 + threadIdx.x;
  out[i] = expf(in[i]);
}

// ---------------- fp32 tiled GEMM: C = A(MxK) * B(KxNc), row-major, batched ----------------
__global__ __launch_bounds__(256)
void gemm_fp32(const float* __restrict__ A, const float* __restrict__ Bm,
               float* __restrict__ C, int K, int Nc,
               long sA, long sB, long sC)
{
  __shared__ __align__(16) float As[16][68];
  __shared__ __align__(16) float Bs[16][68];
  const int b = blockIdx.z;
  A  += (long)b*sA;
  Bm += (long)b*sB;
  C  += (long)b*sC;
  const int tid = threadIdx.x;
  const int tx = tid & 15, ty = tid >> 4;
  const int row0 = blockIdx.x*64, col0 = blockIdx.y*64;
  const int aM = tid >> 2, aK = (tid & 3) << 2;
  const int bK = tid >> 4, bN = (tid & 15) << 2;
  float acc[4][4] = {};
  const float* Aptr = A + (long)(row0+aM)*K + aK;
  const float* Bptr = Bm + (long)bK*Nc + col0 + bN;
  for (int k0=0; k0<K; k0+=16) {
    float4 av = *(const float4*)(Aptr + k0);
    float4 bv = *(const float4*)(Bptr + (long)k0*Nc);
    __syncthreads();
    As[aK+0][aM]=av.x; As[aK+1][aM]=av.y; As[aK+2][aM]=av.z; As[aK+3][aM]=av.w;
    *(float4*)&Bs[bK][bN] = bv;
    __syncthreads();
#pragma unroll
    for (int k=0;k<16;k++){
      float4 a4 = *(const float4*)&As[k][ty<<2];
      float4 b4 = *(const float4*)&Bs[k][tx<<2];
      float aa[4] = {a4.x,a4.y,a4.z,a4.w};
      float bb[4] = {b4.x,b4.y,b4.z,b4.w};
#pragma unroll
      for (int ii=0;ii<4;ii++)
#pragma unroll
        for (int jj=0;jj<4;jj++)
          acc[ii][jj] = fmaf(aa[ii], bb[jj], acc[ii][jj]);
    }
  }
#pragma unroll
  for (int ii=0;ii<4;ii++){
    float4 v = make_float4(acc[ii][0],acc[ii][1],acc[ii][2],acc[ii][3]);
    *(float4*)&C[(long)(row0+(ty<<2)+ii)*Nc + col0 + (tx<<2)] = v;
  }
}

// ---------------- phase 4: row LSE over D; writes logT, E=exp(logT), sumT ----------------
__global__ __launch_bounds__(256)
void rowA_kernel(const float* __restrict__ x, const float* __restrict__ P2,
                 const float* __restrict__ Z, const float* __restrict__ logS,
                 const float* __restrict__ logMu, float* __restrict__ logT,
                 float* __restrict__ E, float* __restrict__ sumT,
                 const float* __restrict__ maskp,
                 const float* __restrict__ a0p, const float* __restrict__ rhop, int it)
{
  __shared__ float sm[4];
  const int bn = blockIdx.x;
  const long base = (long)bn * D_;
  const float a0 = a0p[it], rho = rhop[it];
  const float inv_rho = 1.f/rho;
  const long i0 = base + threadIdx.x, i1 = i0 + 256;
  float y0 = (x[i0] + a0*P2[i0] - Z[i0])*inv_rho + logS[i0];
  float y1 = (x[i1] + a0*P2[i1] - Z[i1])*inv_rho + logS[i1];
  float M = blockMax(fmaxf(y0,y1), sm);
  float S = blockSum(expf(y0-M)+expf(y1-M), sm);
  float lse = M + logf(S);
  float msk = maskp[bn];
  float lt0 = logMu[i0] - lse + y0;
  float lt1 = logMu[i1] - lse + y1;
  logT[i0]=lt0; logT[i1]=lt1;
  float e0 = expf(lt0), e1 = expf(lt1);
  E[i0]=e0; E[i1]=e1;
  float TS = blockSum((e0+e1)*msk, sm);
  if (threadIdx.x==0) sumT[bn] = TS;
}

// ---------------- col pass 1: y' = (Z + a0*P2 + rho*logT)/(a1+rho) -> P2; online-LSE partials ----------------
__global__ __launch_bounds__(256)
void colS1_kernel(float* __restrict__ P2, const float* __restrict__ Z,
                  const float* __restrict__ logT,
                  float* __restrict__ pMax, float* __restrict__ pSum,
                  const float* __restrict__ a0p, const float* __restrict__ a1p,
                  const float* __restrict__ rhop, int it)
{
  const int d = blockIdx.x*256 + threadIdx.x;
  const int ch = blockIdx.y, b = blockIdx.z;
  const float a0=a0p[it], rho=rhop[it];
  const float inv = 1.f/(a1p[it]+rho);
  long i = (long)b*N_*D_ + (long)(ch*CHUNK)*D_ + d;
  float m = -INFINITY, s = 0.f;
  for (int n=0;n<CHUNK;n++, i+=D_){
    float yv = (Z[i] + a0*P2[i] + rho*logT[i])*inv;
    P2[i] = yv;
    float mn = fmaxf(m,yv);
    s = s*expf(m-mn) + expf(yv-mn);
    m = mn;
  }
  long pi = ((long)(b*D_+d))*CH + ch;
  pMax[pi]=m; pSum[pi]=s;
}

__global__ __launch_bounds__(256)
void colCombine_kernel(const float* __restrict__ pMax, const float* __restrict__ pSum,
                       float* __restrict__ Mout, float* __restrict__ sumS, int zeroSumS)
{
  int idx = blockIdx.x*256 + threadIdx.x;   // 0..B*D-1
  float M = -INFINITY;
#pragma unroll
  for (int c=0;c<CH;c++) M = fmaxf(M, pMax[(long)idx*CH+c]);
  float S = 0.f;
#pragma unroll
  for (int c=0;c<CH;c++) S += pSum[(long)idx*CH+c]*expf(pMax[(long)idx*CH+c]-M);
  Mout[idx] = M + logf(S);
  if (zeroSumS) sumS[idx] = 0.f;
}

// ---------------- col pass 2: logS, s, t, Z update, column sums of s ----------------
__global__ __launch_bounds__(256)
void colS2_kernel(const float* __restrict__ Yp, const float* __restrict__ E,
                  float* __restrict__ logS, float* __restrict__ Z,
                  const float* __restrict__ logEta, const float* __restrict__ Mcol,
                  float* __restrict__ sumS, const float* __restrict__ maskp,
                  const float* __restrict__ rhop, int it)
{
  const int d = blockIdx.x*256 + threadIdx.x;
  const int ch = blockIdx.y, b = blockIdx.z;
  const float rho = rhop[it];
  const float lseC = Mcol[b*D_+d];
  long i = (long)b*N_*D_ + (long)(ch*CHUNK)*D_ + d;
  float acc = 0.f;
  for (int n=0;n<CHUNK;n++, i+=D_){
    int gn = ch*CHUNK + n;
    float msk = maskp[b*N_+gn];
    float ls = logEta[i] - lseC + Yp[i];
    logS[i] = ls;
    float s = expf(ls)*msk;
    float t = E[i]*msk;
    Z[i] += rho*(t - s);
    acc += s;
  }
  atomicAdd(&sumS[b*D_+d], acc);
}

// ---------------- phase 8a: log_mu row update + z1 ----------------
__global__ __launch_bounds__(256)
void rowMu_kernel(float* __restrict__ logMu, float* __restrict__ Z1,
                  const float* __restrict__ p0, const float* __restrict__ sumT,
                  const float* __restrict__ a2p, const float* __restrict__ rhop, int it)
{
  __shared__ float sm[4];
  const int bn = blockIdx.x;
  const int b = bn >> 10;
  const long base = (long)bn * D_;
  const float a2 = a2p[it], rho = rhop[it];
  const float inv = 1.f/(rho+a2);
  const int d0 = threadIdx.x, d1 = d0+256;
  const long i0 = base + d0, i1 = base + d1;
  float y0 = (rho*logMu[i0] + a2*logf(p0[b*D_+d0]) - Z1[i0])*inv;
  float y1 = (rho*logMu[i1] + a2*logf(p0[b*D_+d1]) - Z1[i1])*inv;
  float M = blockMax(fmaxf(y0,y1), sm);
  float S = blockSum(expf(y0-M)+expf(y1-M), sm);
  float lse = M + logf(S);
  float st = sumT[bn];
  float lm0 = y0 - lse, lm1 = y1 - lse;
  logMu[i0]=lm0; logMu[i1]=lm1;
  Z1[i0] += rho*(expf(lm0) - st);
  Z1[i1] += rho*(expf(lm1) - st);
}

// ---------------- phase 8b: log_eta col pass 1 (y -> Ybuf, online-LSE partials) ----------------
__global__ __launch_bounds__(256)
void colEta1_kernel(const float* __restrict__ logEta, const float* __restrict__ q0,
                    const float* __restrict__ Z2, float* __restrict__ Ybuf,
                    float* __restrict__ pMax, float* __restrict__ pSum,
                    const float* __restrict__ a3p, const float* __restrict__ rhop, int it)
{
  const int d = blockIdx.x*256 + threadIdx.x;
  const int ch = blockIdx.y, b = blockIdx.z;
  const float a3 = a3p[it], rho = rhop[it];
  const float inv = 1.f/(rho+a3);
  long i = (long)b*N_*D_ + (long)(ch*CHUNK)*D_ + d;
  float m = -INFINITY, s = 0.f;
  for (int n=0;n<CHUNK;n++, i+=D_){
    int gn = ch*CHUNK + n;
    float lq0 = logf(q0[b*N_+gn] + EPSF);
    float yv = (rho*logEta[i] + a3*lq0 - Z2[i])*inv;
    Ybuf[i] = yv;
    float mn = fmaxf(m,yv);
    s = s*expf(m-mn) + expf(yv-mn);
    m = mn;
  }
  long pi = ((long)(b*D_+d))*CH + ch;
  pMax[pi]=m; pSum[pi]=s;
}

// ---------------- phase 8b cont: log_eta update + z2 ----------------
__global__ __launch_bounds__(256)
void colEta2_kernel(const float* __restrict__ Ybuf, float* __restrict__ logEta,
                    float* __restrict__ Z2, const float* __restrict__ Mcol,
                    const float* __restrict__ sumS,
                    const float* __restrict__ rhop, int it)
{
  const int d = blockIdx.x*256 + threadIdx.x;
  const int ch = blockIdx.y, b = blockIdx.z;
  const float rho = rhop[it];
  const float lseC = Mcol[b*D_+d];
  const float ss = sumS[b*D_+d];
  long i = (long)b*N_*D_ + (long)(ch*CHUNK)*D_ + d;
  for (int n=0;n<CHUNK;n++, i+=D_){
    float le = Ybuf[i] - lseC;
    logEta[i] = le;
    Z2[i] += rho*(expf(le) - ss);
  }
}

__global__ __launch_bounds__(256)
void final_kernel(float* __restrict__ E, const float* __restrict__ maskp)
{
  long i = (long)blockIdx.x*256 + threadIdx.x;
  long bn = i >> 9;
  E[i] = E[i]*maskp[bn];
}

// ---------------- launch ----------------
extern "C" void kernel_launch(void* const* d_in, const int* in_sizes, int n_in,
                              void* d_out, int out_size, void* d_ws, size_t ws_size,
                              hipStream_t stream)
{
  const float* x    = (const float*)d_in[0];
  const float* c1   = (const float*)d_in[1];
  const float* c2   = (const float*)d_in[2];
  const float* p0   = (const float*)d_in[3];
  const float* q0   = (const float*)d_in[4];
  const float* a0   = (const float*)d_in[5];
  const float* a1   = (const float*)d_in[6];
  const float* a2   = (const float*)d_in[7];
  const float* a3   = (const float*)d_in[8];
  const float* rho  = (const float*)d_in[9];
  const float* mask = (const float*)d_in[10];

  const size_t BND = (size_t)B_*N_*D_;
  float* w = (float*)d_ws;
  float* logT   = w + 0*BND;
  float* logS   = w + 1*BND;
  float* Z      = w + 2*BND;
  float* logMu  = w + 3*BND;
  float* logEta = w + 4*BND;
  float* Z1     = w + 5*BND;
  float* Z2     = w + 6*BND;
  float* T1     = w + 7*BND;
  float* P2     = w + 8*BND;
  float* small  = w + 9*BND;
  float* sumT = small;                  // B*N
  float* sumS = sumT + B_*N_;           // B*D
  float* Mcol = sumS + B_*D_;           // B*D
  float* pMax = Mcol + B_*D_;           // B*D*CH
  float* pSum = pMax + (size_t)B_*D_*CH;
  float* E    = (float*)d_out;          // alias exp-buffer onto output (16 MB saved in ws)

  dim3 blk(256);
  const int gBND = (int)(BND/256);      // 16384
  dim3 gG(16, 8, 8);                    // M/64, Nc/64, B
  dim3 gCol(D_/256, CH, B_);            // (2,16,8)

  init_kernel<<<gBND, blk, 0, stream>>>(logT, logS, Z, logMu, logEta, Z1, Z2, p0, q0);

  const long sC2 = (long)N_*N_, sND = (long)N_*D_, sC1 = (long)D_*D_;
  for (int it=0; it<4; ++it) {
    // ---- log_t update ----
    exp_kernel<<<gBND, blk, 0, stream>>>(logS, E);
    gemm_fp32<<<gG, blk, 0, stream>>>(c2, E, T1, N_, D_, sC2, sND, sND);
    gemm_fp32<<<gG, blk, 0, stream>>>(T1, c1, P2, D_, D_, sND, sC1, sND);
    rowA_kernel<<<B_*N_, blk, 0, stream>>>(x, P2, Z, logS, logMu, logT, E, sumT, mask, a0, rho, it);
    // ---- log_s update ----
    gemm_fp32<<<gG, blk, 0, stream>>>(c2, E, T1, N_, D_, sC2, sND, sND);
    gemm_fp32<<<gG, blk, 0, stream>>>(T1, c1, P2, D_, D_, sND, sC1, sND);
    colS1_kernel<<<gCol, blk, 0, stream>>>(P2, Z, logT, pMax, pSum, a0, a1, rho, it);
    colCombine_kernel<<<B_*D_/256, blk, 0, stream>>>(pMax, pSum, Mcol, sumS, 1);
    colS2_kernel<<<gCol, blk, 0, stream>>>(P2, E, logS, Z, logEta, Mcol, sumS, mask, rho, it);
    // ---- marginals ----
    rowMu_kernel<<<B_*N_, blk, 0, stream>>>(logMu, Z1, p0, sumT, a2, rho, it);
    colEta1_kernel<<<gCol, blk, 0, stream>>>(logEta, q0, Z2, T1, pMax, pSum, a3, rho, it);
    colCombine_kernel<<<B_*D_/256, blk, 0, stream>>>(pMax, pSum, Mcol, sumS, 0);
    colEta2_kernel<<<gCol, blk, 0, stream>>>(T1, logEta, Z2, Mcol, sumS, rho, it);
  }
  final_kernel<<<gBND, blk, 0, stream>>>(E, mask);
}

// Round 3
// 912.316 us; speedup vs baseline: 2.2352x; 2.2352x over previous
//
#include <hip/hip_runtime.h>
#include <math.h>

#define B_ 8
#define N_ 1024
#define D_ 512
#define CH 16
#define CHUNK (N_/CH)   /* 64 rows per column-chunk */
#define EPSF 1e-8f

typedef unsigned short u16;
typedef __attribute__((ext_vector_type(8))) short bf16x8;
typedef __attribute__((ext_vector_type(4))) float f32x4;

static __device__ __forceinline__ u16 f2bf(float f){
  unsigned int u = __builtin_bit_cast(unsigned int, f);
  u = (u + 0x7FFFu + ((u >> 16) & 1u)) >> 16;
  return (u16)u;
}

// ---------------- reduction helpers (256-thread blocks = 4 waves) ----------------
static __device__ __forceinline__ float wredMax(float v){
#pragma unroll
  for (int o=32;o>=1;o>>=1) v = fmaxf(v, __shfl_xor(v,o,64));
  return v;
}
static __device__ __forceinline__ float wredSum(float v){
#pragma unroll
  for (int o=32;o>=1;o>>=1) v += __shfl_xor(v,o,64);
  return v;
}
static __device__ __forceinline__ float blockMax(float v, float* sm){
  v = wredMax(v);
  int w = threadIdx.x>>6, l = threadIdx.x&63;
  if (l==0) sm[w]=v;
  __syncthreads();
  float r = fmaxf(fmaxf(sm[0],sm[1]),fmaxf(sm[2],sm[3]));
  __syncthreads();
  return r;
}
static __device__ __forceinline__ float blockSum(float v, float* sm){
  v = wredSum(v);
  int w = threadIdx.x>>6, l = threadIdx.x&63;
  if (l==0) sm[w]=v;
  __syncthreads();
  float r = (sm[0]+sm[1])+(sm[2]+sm[3]);
  __syncthreads();
  return r;
}

// ---------------- init: materialize state as (B,N,D) ----------------
__global__ __launch_bounds__(256)
void init_kernel(float* __restrict__ logS,
                 float* __restrict__ Z, float* __restrict__ logMu,
                 float* __restrict__ logEta, float* __restrict__ Z1,
                 float* __restrict__ Z2,
                 const float* __restrict__ p0, const float* __restrict__ q0)
{
  long i = (long)blockIdx.x*256 + threadIdx.x;
  int d  = (int)(i & (D_-1));
  long bn = i >> 9;               // i / D_
  int b  = (int)(bn >> 10);       // bn / N_
  float p = p0[b*D_ + d];
  float q = q0[bn];
  logS[i] = logf(q*p + EPSF);
  Z[i] = 0.f;
  logMu[i]  = logf(p);
  logEta[i] = logf(q + EPSF);
  Z1[i] = 0.f;
  Z2[i] = 0.f;
}

// ---------------- transpose (+optional exp) fp32 [R][C] -> bf16 [C][R], per batch ----------------
template<int DOEXP>
__global__ __launch_bounds__(256)
void texp_kernel(const float* __restrict__ src, u16* __restrict__ dst, int R, int Ccols)
{
  __shared__ float tile[64][65];
  const int b = blockIdx.z;
  const long bb = (long)b*R*Ccols;
  const int r0 = blockIdx.x*64, c0 = blockIdx.y*64;
  const int c = threadIdx.x & 63, rr = threadIdx.x >> 6;
#pragma unroll
  for (int i=0;i<16;i++){
    int r = i*4 + rr;
    float v = src[bb + (long)(r0+r)*Ccols + c0 + c];
    if (DOEXP) v = expf(v);
    tile[r][c] = v;
  }
  __syncthreads();
#pragma unroll
  for (int i=0;i<16;i++){
    int r = i*4 + rr;
    dst[bb + (long)(c0+r)*R + r0 + c] = f2bf(tile[c][r]);
  }
}

// ---------------- bf16 MFMA GEMM: C[M][Nc] = A[M][K] * Bt[Nc][K]^T, batched ----------------
// 128x128 tile, BK=64, 256 threads = 4 waves in 2x2 grid, each wave 64x64 (4x4 16x16 frags).
// LDS rows padded to 72 bf16 (144B) -> frag ds_read_b128 is 2-way on banks (free).
template<int K, int A_FP32, int OUT_BF16>
__global__ __launch_bounds__(256)
void gemm_mfma(const float* __restrict__ Af, const u16* __restrict__ Ab,
               const u16* __restrict__ Btb, void* __restrict__ Cp,
               long sA, long sB, long sC, int ldc)
{
  __shared__ __attribute__((aligned(16))) u16 As[128*72];
  __shared__ __attribute__((aligned(16))) u16 Bs[128*72];
  const int t = threadIdx.x;
  const int bx = blockIdx.x, by = blockIdx.y, b = blockIdx.z;
  const int row0 = bx*128, col0 = by*128;
  const int w = t>>6, l = t&63, lr = l&15, lg = l>>4;
  const int wm = w>>1, wn = w&1;

  f32x4 acc[4][4];
#pragma unroll
  for (int m=0;m<4;m++)
#pragma unroll
    for (int n=0;n<4;n++) acc[m][n] = (f32x4){0.f,0.f,0.f,0.f};

  for (int k0 = 0; k0 < K; k0 += 64) {
    __syncthreads();
    if constexpr (A_FP32) {
      const float* Abase = Af + (long)b*sA + (long)row0*K + k0;
#pragma unroll
      for (int i=0;i<8;i++){
        int g = i*256 + t;           // 0..2047 granules of 4 floats
        int r = g>>4, c4 = g&15;
        float4 v = *(const float4*)(Abase + (long)r*K + c4*4);
        ushort4 u;
        u.x=f2bf(v.x); u.y=f2bf(v.y); u.z=f2bf(v.z); u.w=f2bf(v.w);
        *(ushort4*)&As[r*72 + c4*4] = u;
      }
    } else {
      const u16* Abase = Ab + (long)b*sA + (long)row0*K + k0;
#pragma unroll
      for (int i=0;i<4;i++){
        int g = i*256 + t;           // 0..1023 granules of 8 bf16
        int r = g>>3, j = g&7;
        bf16x8 v = *(const bf16x8*)(Abase + (long)r*K + j*8);
        *(bf16x8*)&As[r*72 + j*8] = v;
      }
    }
    {
      const u16* Bbase = Btb + (long)b*sB + (long)col0*K + k0;
#pragma unroll
      for (int i=0;i<4;i++){
        int g = i*256 + t;
        int r = g>>3, j = g&7;
        bf16x8 v = *(const bf16x8*)(Bbase + (long)r*K + j*8);
        *(bf16x8*)&Bs[r*72 + j*8] = v;
      }
    }
    __syncthreads();
#pragma unroll
    for (int kk=0;kk<2;kk++){
      bf16x8 a[4], bb[4];
#pragma unroll
      for (int m=0;m<4;m++)
        a[m] = *(const bf16x8*)&As[(wm*64 + m*16 + lr)*72 + kk*32 + lg*8];
#pragma unroll
      for (int n=0;n<4;n++)
        bb[n] = *(const bf16x8*)&Bs[(wn*64 + n*16 + lr)*72 + kk*32 + lg*8];
#pragma unroll
      for (int m=0;m<4;m++)
#pragma unroll
        for (int n=0;n<4;n++)
          acc[m][n] = __builtin_amdgcn_mfma_f32_16x16x32_bf16(a[m], bb[n], acc[m][n], 0, 0, 0);
    }
  }

  // epilogue: D frag mapping col=lane&15, row=(lane>>4)*4+reg  [m89-verified]
  if constexpr (OUT_BF16) {
    u16* C = (u16*)Cp + (long)b*sC;
#pragma unroll
    for (int m=0;m<4;m++)
#pragma unroll
      for (int n=0;n<4;n++){
        int grow = row0 + wm*64 + m*16 + lg*4;
        int gcol = col0 + wn*64 + n*16 + lr;
#pragma unroll
        for (int r4=0;r4<4;r4++)
          C[(long)(grow+r4)*ldc + gcol] = f2bf(acc[m][n][r4]);
      }
  } else {
    float* C = (float*)Cp + (long)b*sC;
#pragma unroll
    for (int m=0;m<4;m++)
#pragma unroll
      for (int n=0;n<4;n++){
        int grow = row0 + wm*64 + m*16 + lg*4;
        int gcol = col0 + wn*64 + n*16 + lr;
#pragma unroll
        for (int r4=0;r4<4;r4++)
          C[(long)(grow+r4)*ldc + gcol] = acc[m][n][r4];
      }
  }
}

// ---------------- phase 4: row LSE over D; writes E=exp(logT), sumT ----------------
__global__ __launch_bounds__(256)
void rowA_kernel(const float* __restrict__ x, const float* __restrict__ P2,
                 const float* __restrict__ Z, const float* __restrict__ logS,
                 const float* __restrict__ logMu,
                 float* __restrict__ E, float* __restrict__ sumT,
                 const float* __restrict__ maskp,
                 const float* __restrict__ a0p, const float* __restrict__ rhop, int it)
{
  __shared__ float sm[4];
  const int bn = blockIdx.x;
  const long base = (long)bn * D_;
  const float a0 = a0p[it], rho = rhop[it];
  const float inv_rho = 1.f/rho;
  const long i0 = base + threadIdx.x, i1 = i0 + 256;
  float y0 = (x[i0] + a0*P2[i0] - Z[i0])*inv_rho + logS[i0];
  float y1 = (x[i1] + a0*P2[i1] - Z[i1])*inv_rho + logS[i1];
  float M = blockMax(fmaxf(y0,y1), sm);
  float S = blockSum(expf(y0-M)+expf(y1-M), sm);
  float lse = M + logf(S);
  float msk = maskp[bn];
  float lt0 = logMu[i0] - lse + y0;
  float lt1 = logMu[i1] - lse + y1;
  float e0 = expf(lt0), e1 = expf(lt1);
  E[i0]=e0; E[i1]=e1;
  float TS = blockSum((e0+e1)*msk, sm);
  if (threadIdx.x==0) sumT[bn] = TS;
}

// ---------------- col pass 1: y' = (Z + a0*P2 + rho*log(E))/(a1+rho) -> P2; online-LSE partials ----------------
__global__ __launch_bounds__(256)
void colS1_kernel(float* __restrict__ P2, const float* __restrict__ Z,
                  const float* __restrict__ E,
                  float* __restrict__ pMax, float* __restrict__ pSum,
                  const float* __restrict__ a0p, const float* __restrict__ a1p,
                  const float* __restrict__ rhop, int it)
{
  const int d = blockIdx.x*256 + threadIdx.x;
  const int ch = blockIdx.y, b = blockIdx.z;
  const float a0=a0p[it], rho=rhop[it];
  const float inv = 1.f/(a1p[it]+rho);
  long i = (long)b*N_*D_ + (long)(ch*CHUNK)*D_ + d;
  float m = -INFINITY, s = 0.f;
  for (int n=0;n<CHUNK;n++, i+=D_){
    float lt = logf(E[i] + 1e-37f);
    float yv = (Z[i] + a0*P2[i] + rho*lt)*inv;
    P2[i] = yv;
    float mn = fmaxf(m,yv);
    s = s*expf(m-mn) + expf(yv-mn);
    m = mn;
  }
  long pi = ((long)(b*D_+d))*CH + ch;
  pMax[pi]=m; pSum[pi]=s;
}

__global__ __launch_bounds__(256)
void colCombine_kernel(const float* __restrict__ pMax, const float* __restrict__ pSum,
                       float* __restrict__ Mout, float* __restrict__ sumS, int zeroSumS)
{
  int idx = blockIdx.x*256 + threadIdx.x;   // 0..B*D-1
  float M = -INFINITY;
#pragma unroll
  for (int c=0;c<CH;c++) M = fmaxf(M, pMax[(long)idx*CH+c]);
  float S = 0.f;
#pragma unroll
  for (int c=0;c<CH;c++) S += pSum[(long)idx*CH+c]*expf(pMax[(long)idx*CH+c]-M);
  Mout[idx] = M + logf(S);
  if (zeroSumS) sumS[idx] = 0.f;
}

// ---------------- col pass 2: logS, s, t, Z update, column sums of s ----------------
__global__ __launch_bounds__(256)
void colS2_kernel(const float* __restrict__ Yp, const float* __restrict__ E,
                  float* __restrict__ logS, float* __restrict__ Z,
                  const float* __restrict__ logEta, const float* __restrict__ Mcol,
                  float* __restrict__ sumS, const float* __restrict__ maskp,
                  const float* __restrict__ rhop, int it)
{
  const int d = blockIdx.x*256 + threadIdx.x;
  const int ch = blockIdx.y, b = blockIdx.z;
  const float rho = rhop[it];
  const float lseC = Mcol[b*D_+d];
  long i = (long)b*N_*D_ + (long)(ch*CHUNK)*D_ + d;
  float acc = 0.f;
  for (int n=0;n<CHUNK;n++, i+=D_){
    int gn = ch*CHUNK + n;
    float msk = maskp[b*N_+gn];
    float ls = logEta[i] - lseC + Yp[i];
    logS[i] = ls;
    float s = expf(ls)*msk;
    float t = E[i]*msk;
    Z[i] += rho*(t - s);
    acc += s;
  }
  atomicAdd(&sumS[b*D_+d], acc);
}

// ---------------- phase 8a: log_mu row update + z1 ----------------
__global__ __launch_bounds__(256)
void rowMu_kernel(float* __restrict__ logMu, float* __restrict__ Z1,
                  const float* __restrict__ p0, const float* __restrict__ sumT,
                  const float* __restrict__ a2p, const float* __restrict__ rhop, int it)
{
  __shared__ float sm[4];
  const int bn = blockIdx.x;
  const int b = bn >> 10;
  const long base = (long)bn * D_;
  const float a2 = a2p[it], rho = rhop[it];
  const float inv = 1.f/(rho+a2);
  const int d0 = threadIdx.x, d1 = d0+256;
  const long i0 = base + d0, i1 = base + d1;
  float y0 = (rho*logMu[i0] + a2*logf(p0[b*D_+d0]) - Z1[i0])*inv;
  float y1 = (rho*logMu[i1] + a2*logf(p0[b*D_+d1]) - Z1[i1])*inv;
  float M = blockMax(fmaxf(y0,y1), sm);
  float S = blockSum(expf(y0-M)+expf(y1-M), sm);
  float lse = M + logf(S);
  float st = sumT[bn];
  float lm0 = y0 - lse, lm1 = y1 - lse;
  logMu[i0]=lm0; logMu[i1]=lm1;
  Z1[i0] += rho*(expf(lm0) - st);
  Z1[i1] += rho*(expf(lm1) - st);
}

// ---------------- phase 8b: log_eta col pass 1 (y -> Ybuf, online-LSE partials) ----------------
__global__ __launch_bounds__(256)
void colEta1_kernel(const float* __restrict__ logEta, const float* __restrict__ q0,
                    const float* __restrict__ Z2, float* __restrict__ Ybuf,
                    float* __restrict__ pMax, float* __restrict__ pSum,
                    const float* __restrict__ a3p, const float* __restrict__ rhop, int it)
{
  const int d = blockIdx.x*256 + threadIdx.x;
  const int ch = blockIdx.y, b = blockIdx.z;
  const float a3 = a3p[it], rho = rhop[it];
  const float inv = 1.f/(rho+a3);
  long i = (long)b*N_*D_ + (long)(ch*CHUNK)*D_ + d;
  float m = -INFINITY, s = 0.f;
  for (int n=0;n<CHUNK;n++, i+=D_){
    int gn = ch*CHUNK + n;
    float lq0 = logf(q0[b*N_+gn] + EPSF);
    float yv = (rho*logEta[i] + a3*lq0 - Z2[i])*inv;
    Ybuf[i] = yv;
    float mn = fmaxf(m,yv);
    s = s*expf(m-mn) + expf(yv-mn);
    m = mn;
  }
  long pi = ((long)(b*D_+d))*CH + ch;
  pMax[pi]=m; pSum[pi]=s;
}

// ---------------- phase 8b cont: log_eta update + z2 ----------------
__global__ __launch_bounds__(256)
void colEta2_kernel(const float* __restrict__ Ybuf, float* __restrict__ logEta,
                    float* __restrict__ Z2, const float* __restrict__ Mcol,
                    const float* __restrict__ sumS,
                    const float* __restrict__ rhop, int it)
{
  const int d = blockIdx.x*256 + threadIdx.x;
  const int ch = blockIdx.y, b = blockIdx.z;
  const float rho = rhop[it];
  const float lseC = Mcol[b*D_+d];
  const float ss = sumS[b*D_+d];
  long i = (long)b*N_*D_ + (long)(ch*CHUNK)*D_ + d;
  for (int n=0;n<CHUNK;n++, i+=D_){
    float le = Ybuf[i] - lseC;
    logEta[i] = le;
    Z2[i] += rho*(expf(le) - ss);
  }
}

__global__ __launch_bounds__(256)
void final_kernel(float* __restrict__ E, const float* __restrict__ maskp)
{
  long i = (long)blockIdx.x*256 + threadIdx.x;
  long bn = i >> 9;
  E[i] = E[i]*maskp[bn];
}

// ---------------- launch ----------------
extern "C" void kernel_launch(void* const* d_in, const int* in_sizes, int n_in,
                              void* d_out, int out_size, void* d_ws, size_t ws_size,
                              hipStream_t stream)
{
  const float* x    = (const float*)d_in[0];
  const float* c1   = (const float*)d_in[1];
  const float* c2   = (const float*)d_in[2];
  const float* p0   = (const float*)d_in[3];
  const float* q0   = (const float*)d_in[4];
  const float* a0   = (const float*)d_in[5];
  const float* a1   = (const float*)d_in[6];
  const float* a2   = (const float*)d_in[7];
  const float* a3   = (const float*)d_in[8];
  const float* rho  = (const float*)d_in[9];
  const float* mask = (const float*)d_in[10];

  const size_t BND = (size_t)B_*N_*D_;           // 4,194,304
  float* w = (float*)d_ws;
  float* logS   = w + 0*BND;
  float* Z      = w + 1*BND;
  float* logMu  = w + 2*BND;
  float* logEta = w + 3*BND;
  float* Z1     = w + 4*BND;
  float* Z2     = w + 5*BND;
  float* P2     = w + 6*BND;                     // GEMM2 out -> colS1 y' -> eta Ybuf
  u16*  Et   = (u16*)(w + 7*BND);                // bf16 [B][D][N]
  u16*  T1b  = Et + BND;                         // bf16 [B][N][D]
  u16*  c1t  = T1b + BND;                        // bf16 [B][D][D] (c1 transposed)
  float* small = (float*)(c1t + (size_t)B_*D_*D_);
  float* sumT = small;                           // B*N
  float* sumS = sumT + B_*N_;                    // B*D
  float* Mcol = sumS + B_*D_;                    // B*D
  float* pMax = Mcol + B_*D_;                    // B*D*CH
  float* pSum = pMax + (size_t)B_*D_*CH;
  float* E    = (float*)d_out;                   // exp(logT), scaled by mask at the end

  dim3 blk(256);
  const int gBND = (int)(BND/256);               // 16384
  dim3 gT1(16, 8, B_);                           // texp:  N/64, D/64, B
  dim3 gTc(8, 8, B_);                            // tconv: D/64, D/64, B
  dim3 gG(8, 4, B_);                             // gemm:  M/128, Nout/128, B
  dim3 gCol(D_/256, CH, B_);                     // (2,16,8)

  const long sC2 = (long)N_*N_, sND = (long)N_*D_, sC1 = (long)D_*D_, sDN = (long)D_*N_;

  init_kernel<<<gBND, blk, 0, stream>>>(logS, Z, logMu, logEta, Z1, Z2, p0, q0);
  texp_kernel<0><<<gTc, blk, 0, stream>>>(c1, c1t, D_, D_);   // c1t = c1^T bf16

  for (int it=0; it<4; ++it) {
    // ---- log_t update: tmp2 = c2 @ exp(logS) @ c1 ----
    texp_kernel<1><<<gT1, blk, 0, stream>>>(logS, Et, N_, D_);
    gemm_mfma<1024,1,1><<<gG, blk, 0, stream>>>(c2, nullptr, Et, T1b, sC2, sDN, sND, D_);
    gemm_mfma< 512,0,0><<<gG, blk, 0, stream>>>(nullptr, T1b, c1t, P2, sND, sC1, sND, D_);
    rowA_kernel<<<B_*N_, blk, 0, stream>>>(x, P2, Z, logS, logMu, E, sumT, mask, a0, rho, it);
    // ---- log_s update: tmp2 = c2 @ exp(logT) @ c1 ----
    texp_kernel<0><<<gT1, blk, 0, stream>>>(E, Et, N_, D_);
    gemm_mfma<1024,1,1><<<gG, blk, 0, stream>>>(c2, nullptr, Et, T1b, sC2, sDN, sND, D_);
    gemm_mfma< 512,0,0><<<gG, blk, 0, stream>>>(nullptr, T1b, c1t, P2, sND, sC1, sND, D_);
    colS1_kernel<<<gCol, blk, 0, stream>>>(P2, Z, E, pMax, pSum, a0, a1, rho, it);
    colCombine_kernel<<<B_*D_/256, blk, 0, stream>>>(pMax, pSum, Mcol, sumS, 1);
    colS2_kernel<<<gCol, blk, 0, stream>>>(P2, E, logS, Z, logEta, Mcol, sumS, mask, rho, it);
    // ---- marginals ----
    rowMu_kernel<<<B_*N_, blk, 0, stream>>>(logMu, Z1, p0, sumT, a2, rho, it);
    colEta1_kernel<<<gCol, blk, 0, stream>>>(logEta, q0, Z2, P2, pMax, pSum, a3, rho, it);
    colCombine_kernel<<<B_*D_/256, blk, 0, stream>>>(pMax, pSum, Mcol, sumS, 0);
    colEta2_kernel<<<gCol, blk, 0, stream>>>(P2, logEta, Z2, Mcol, sumS, rho, it);
  }
  final_kernel<<<gBND, blk, 0, stream>>>(E, mask);
}

// Round 6
// 824.557 us; speedup vs baseline: 2.4731x; 1.1064x over previous
//
#include <hip/hip_runtime.h>
#include <math.h>

#define B_ 8
#define N_ 1024
#define D_ 512
#define CH 16
#define CHUNK (N_/CH)   /* 64 rows per column-chunk */
#define EPSF 1e-8f

typedef unsigned short u16;
typedef __attribute__((ext_vector_type(8))) short bf16x8;
typedef __attribute__((ext_vector_type(4))) float f32x4;

static __device__ __forceinline__ u16 f2bf(float f){
  unsigned int u = __builtin_bit_cast(unsigned int, f);
  u = (u + 0x7FFFu + ((u >> 16) & 1u)) >> 16;
  return (u16)u;
}

// ---------------- reduction helpers (256-thread blocks = 4 waves) ----------------
static __device__ __forceinline__ float wredMax(float v){
#pragma unroll
  for (int o=32;o>=1;o>>=1) v = fmaxf(v, __shfl_xor(v,o,64));
  return v;
}
static __device__ __forceinline__ float wredSum(float v){
#pragma unroll
  for (int o=32;o>=1;o>>=1) v += __shfl_xor(v,o,64);
  return v;
}
static __device__ __forceinline__ float blockMax(float v, float* sm){
  v = wredMax(v);
  int w = threadIdx.x>>6, l = threadIdx.x&63;
  if (l==0) sm[w]=v;
  __syncthreads();
  float r = fmaxf(fmaxf(sm[0],sm[1]),fmaxf(sm[2],sm[3]));
  __syncthreads();
  return r;
}
static __device__ __forceinline__ float blockSum(float v, float* sm){
  v = wredSum(v);
  int w = threadIdx.x>>6, l = threadIdx.x&63;
  if (l==0) sm[w]=v;
  __syncthreads();
  float r = (sm[0]+sm[1])+(sm[2]+sm[3]);
  __syncthreads();
  return r;
}

// ---------------- init: materialize state as (B,N,D) ----------------
__global__ __launch_bounds__(256)
void init_kernel(float* __restrict__ logS,
                 float* __restrict__ Z, float* __restrict__ logMu,
                 float* __restrict__ logEta, float* __restrict__ Z1,
                 float* __restrict__ Z2,
                 const float* __restrict__ p0, const float* __restrict__ q0)
{
  long i = (long)blockIdx.x*256 + threadIdx.x;
  int d  = (int)(i & (D_-1));
  long bn = i >> 9;               // i / D_
  int b  = (int)(bn >> 10);       // bn / N_
  float p = p0[b*D_ + d];
  float q = q0[bn];
  logS[i] = logf(q*p + EPSF);
  Z[i] = 0.f;
  logMu[i]  = logf(p);
  logEta[i] = logf(q + EPSF);
  Z1[i] = 0.f;
  Z2[i] = 0.f;
}

// initEt: EtA[b][d][n] = bf16(q0[b][n]*p0[b][d] + eps)  (= exp(logS)^T for iter 0)
__global__ __launch_bounds__(256)
void initEt_kernel(u16* __restrict__ Et, const float* __restrict__ p0,
                   const float* __restrict__ q0)
{
  long i = (long)blockIdx.x*256 + threadIdx.x;   // over B*D*N
  int n = (int)(i & (N_-1));
  long bd = i >> 10;
  int d = (int)(bd & (D_-1));
  int b = (int)(bd >> 9);
  Et[i] = f2bf(p0[b*D_+d]*q0[b*N_+n] + EPSF);
}

// ---------------- transpose-convert fp32 [R][C] -> bf16 [C][R], per batch ----------------
__global__ __launch_bounds__(256)
void tconv_kernel(const float* __restrict__ src, u16* __restrict__ dst, int R, int Ccols)
{
  __shared__ float tile[64][65];
  const int b = blockIdx.z;
  const long bb = (long)b*R*Ccols;
  const int r0 = blockIdx.x*64, c0 = blockIdx.y*64;
  const int c = threadIdx.x & 63, rr = threadIdx.x >> 6;
#pragma unroll
  for (int i=0;i<16;i++){
    int r = i*4 + rr;
    tile[r][c] = src[bb + (long)(r0+r)*Ccols + c0 + c];
  }
  __syncthreads();
#pragma unroll
  for (int i=0;i<16;i++){
    int r = i*4 + rr;
    dst[bb + (long)(c0+r)*R + r0 + c] = f2bf(tile[c][r]);
  }
}

// ---------------- bf16 MFMA GEMM: C[M][Nc] = A[M][K] * Bt[Nc][K]^T, batched ----------------
// 128x64 tile, BK=64, 256 threads = 4 waves (2x2), each wave 64x32 (acc[4][2]).
// LDS rows padded to 72 bf16 (144B). Register-prefetch of next K-step hides HBM latency.
template<int K, int A_FP32, int OUT_BF16>
__global__ __launch_bounds__(256)
void gemm_mfma(const float* __restrict__ Af, const u16* __restrict__ Ab,
               const u16* __restrict__ Btb, void* __restrict__ Cp,
               long sA, long sB, long sC, int ldc)
{
  __shared__ __attribute__((aligned(16))) u16 As[128*72];
  __shared__ __attribute__((aligned(16))) u16 Bs[64*72];
  const int t = threadIdx.x;
  const int b = blockIdx.z;
  const int row0 = blockIdx.x*128, col0 = blockIdx.y*64;
  const int w = t>>6, l = t&63, lr = l&15, lg = l>>4;
  const int wm = w>>1, wn = w&1;

  f32x4 acc[4][2];
#pragma unroll
  for (int m=0;m<4;m++)
#pragma unroll
    for (int n=0;n<2;n++) acc[m][n] = (f32x4){0.f,0.f,0.f,0.f};

  const float* Afb = Af ? (Af + (long)b*sA + (long)row0*K) : nullptr;
  const u16*  Abb = Ab ? (Ab + (long)b*sA + (long)row0*K) : nullptr;
  const u16*  Bbb = Btb + (long)b*sB + (long)col0*K;

  float4 pa[8];
  bf16x8 qa[4];
  bf16x8 qb[2];

  // ---- preload K-step 0 ----
  if constexpr (A_FP32) {
#pragma unroll
    for (int i=0;i<8;i++){ int g=i*256+t; int r=g>>4, c4=g&15;
      pa[i] = *(const float4*)(Afb + (long)r*K + c4*4); }
  } else {
#pragma unroll
    for (int i=0;i<4;i++){ int g=i*256+t; int r=g>>3, j=g&7;
      qa[i] = *(const bf16x8*)(Abb + (long)r*K + j*8); }
  }
#pragma unroll
  for (int i=0;i<2;i++){ int g=i*256+t; int r=g>>3, j=g&7;
    qb[i] = *(const bf16x8*)(Bbb + (long)r*K + j*8); }

  for (int k0 = 0; k0 < K; k0 += 64) {
    __syncthreads();
    // ---- regs -> LDS ----
    if constexpr (A_FP32) {
#pragma unroll
      for (int i=0;i<8;i++){ int g=i*256+t; int r=g>>4, c4=g&15;
        ushort4 u;
        u.x=f2bf(pa[i].x); u.y=f2bf(pa[i].y); u.z=f2bf(pa[i].z); u.w=f2bf(pa[i].w);
        *(ushort4*)&As[r*72 + c4*4] = u; }
    } else {
#pragma unroll
      for (int i=0;i<4;i++){ int g=i*256+t; int r=g>>3, j=g&7;
        *(bf16x8*)&As[r*72 + j*8] = qa[i]; }
    }
#pragma unroll
    for (int i=0;i<2;i++){ int g=i*256+t; int r=g>>3, j=g&7;
      *(bf16x8*)&Bs[r*72 + j*8] = qb[i]; }
    __syncthreads();
    // ---- issue next K-step's loads (hide under MFMA) ----
    if (k0 + 64 < K) {
      int kn = k0 + 64;
      if constexpr (A_FP32) {
#pragma unroll
        for (int i=0;i<8;i++){ int g=i*256+t; int r=g>>4, c4=g&15;
          pa[i] = *(const float4*)(Afb + (long)r*K + kn + c4*4); }
      } else {
#pragma unroll
        for (int i=0;i<4;i++){ int g=i*256+t; int r=g>>3, j=g&7;
          qa[i] = *(const bf16x8*)(Abb + (long)r*K + kn + j*8); }
      }
#pragma unroll
      for (int i=0;i<2;i++){ int g=i*256+t; int r=g>>3, j=g&7;
        qb[i] = *(const bf16x8*)(Bbb + (long)r*K + kn + j*8); }
    }
    // ---- compute ----
#pragma unroll
    for (int kk=0;kk<2;kk++){
      bf16x8 afr[4], bfr[2];
#pragma unroll
      for (int m=0;m<4;m++)
        afr[m] = *(const bf16x8*)&As[(wm*64 + m*16 + lr)*72 + kk*32 + lg*8];
#pragma unroll
      for (int n=0;n<2;n++)
        bfr[n] = *(const bf16x8*)&Bs[(wn*32 + n*16 + lr)*72 + kk*32 + lg*8];
#pragma unroll
      for (int m=0;m<4;m++)
#pragma unroll
        for (int n=0;n<2;n++)
          acc[m][n] = __builtin_amdgcn_mfma_f32_16x16x32_bf16(afr[m], bfr[n], acc[m][n], 0, 0, 0);
    }
  }

  // epilogue: D frag mapping col=lane&15, row=(lane>>4)*4+reg  [m89-verified]
  if constexpr (OUT_BF16) {
    u16* C = (u16*)Cp + (long)b*sC;
#pragma unroll
    for (int m=0;m<4;m++)
#pragma unroll
      for (int n=0;n<2;n++){
        int grow = row0 + wm*64 + m*16 + lg*4;
        int gcol = col0 + wn*32 + n*16 + lr;
#pragma unroll
        for (int r4=0;r4<4;r4++)
          C[(long)(grow+r4)*ldc + gcol] = f2bf(acc[m][n][r4]);
      }
  } else {
    float* C = (float*)Cp + (long)b*sC;
#pragma unroll
    for (int m=0;m<4;m++)
#pragma unroll
      for (int n=0;n<2;n++){
        int grow = row0 + wm*64 + m*16 + lg*4;
        int gcol = col0 + wn*32 + n*16 + lr;
#pragma unroll
        for (int r4=0;r4<4;r4++)
          C[(long)(grow+r4)*ldc + gcol] = acc[m][n][r4];
      }
  }
}

// ---------------- phase 4: row LSE over D; writes E=exp(logT), sumT ----------------
__global__ __launch_bounds__(256)
void rowA_kernel(const float* __restrict__ x, const float* __restrict__ P2,
                 const float* __restrict__ Z, const float* __restrict__ logS,
                 const float* __restrict__ logMu,
                 float* __restrict__ E, float* __restrict__ sumT,
                 const float* __restrict__ maskp,
                 const float* __restrict__ a0p, const float* __restrict__ rhop, int it)
{
  __shared__ float sm[4];
  const int bn = blockIdx.x;
  const long base = (long)bn * D_;
  const float a0 = a0p[it], rho = rhop[it];
  const float inv_rho = 1.f/rho;
  const long i0 = base + threadIdx.x, i1 = i0 + 256;
  float y0 = (x[i0] + a0*P2[i0] - Z[i0])*inv_rho + logS[i0];
  float y1 = (x[i1] + a0*P2[i1] - Z[i1])*inv_rho + logS[i1];
  float M = blockMax(fmaxf(y0,y1), sm);
  float S = blockSum(expf(y0-M)+expf(y1-M), sm);
  float lse = M + logf(S);
  float msk = maskp[bn];
  float lt0 = logMu[i0] - lse + y0;
  float lt1 = logMu[i1] - lse + y1;
  float e0 = expf(lt0), e1 = expf(lt1);
  E[i0]=e0; E[i1]=e1;
  float TS = blockSum((e0+e1)*msk, sm);
  if (threadIdx.x==0) sumT[bn] = TS;
}

// ---------------- col pass 1: y' = (Z + a0*P2 + rho*log(E))/(a1+rho) -> P2; online-LSE partials ----------------
__global__ __launch_bounds__(256)
void colS1_kernel(float* __restrict__ P2, const float* __restrict__ Z,
                  const float* __restrict__ E,
                  float* __restrict__ pMax, float* __restrict__ pSum,
                  const float* __restrict__ a0p, const float* __restrict__ a1p,
                  const float* __restrict__ rhop, int it)
{
  const int d = blockIdx.x*256 + threadIdx.x;
  const int ch = blockIdx.y, b = blockIdx.z;
  const float a0=a0p[it], rho=rhop[it];
  const float inv = 1.f/(a1p[it]+rho);
  long i = (long)b*N_*D_ + (long)(ch*CHUNK)*D_ + d;
  float m = -INFINITY, s = 0.f;
  for (int n=0;n<CHUNK;n++, i+=D_){
    float lt = logf(E[i] + 1e-37f);
    float yv = (Z[i] + a0*P2[i] + rho*lt)*inv;
    P2[i] = yv;
    float mn = fmaxf(m,yv);
    s = s*expf(m-mn) + expf(yv-mn);
    m = mn;
  }
  long pi = ((long)(b*D_+d))*CH + ch;
  pMax[pi]=m; pSum[pi]=s;
}

__global__ __launch_bounds__(256)
void colCombine_kernel(const float* __restrict__ pMax, const float* __restrict__ pSum,
                       float* __restrict__ Mout, float* __restrict__ sumS, int zeroSumS)
{
  int idx = blockIdx.x*256 + threadIdx.x;   // 0..B*D-1
  float M = -INFINITY;
#pragma unroll
  for (int c=0;c<CH;c++) M = fmaxf(M, pMax[(long)idx*CH+c]);
  float S = 0.f;
#pragma unroll
  for (int c=0;c<CH;c++) S += pSum[(long)idx*CH+c]*expf(pMax[(long)idx*CH+c]-M);
  Mout[idx] = M + logf(S);
  if (zeroSumS) sumS[idx] = 0.f;
}

// ---------------- col pass 2: logS, s, t, Z update, sumS; FUSED: EtA = bf16(exp(logS))^T ----------------
__global__ __launch_bounds__(256)
void colS2_kernel(const float* __restrict__ Yp, const float* __restrict__ E,
                  float* __restrict__ logS, float* __restrict__ Z,
                  const float* __restrict__ logEta, const float* __restrict__ Mcol,
                  float* __restrict__ sumS, const float* __restrict__ maskp,
                  u16* __restrict__ Et,
                  const float* __restrict__ rhop, int it)
{
  __shared__ u16 tile[64][260];      // 64 n-rows x 256 d-cols (+pad)
  const int tid = threadIdx.x;
  const int d0 = blockIdx.x*256;
  const int d = d0 + tid;
  const int ch = blockIdx.y, b = blockIdx.z;
  const int n0 = ch*CHUNK;
  const float rho = rhop[it];
  const float lseC = Mcol[b*D_+d];
  long i = (long)b*N_*D_ + (long)n0*D_ + d;
  float acc = 0.f;
  for (int n=0;n<CHUNK;n++, i+=D_){
    int gn = n0 + n;
    float msk = maskp[b*N_+gn];
    float ls = logEta[i] - lseC + Yp[i];
    logS[i] = ls;
    float es = expf(ls);
    tile[n][tid] = f2bf(es);
    float s = es*msk;
    float t = E[i]*msk;
    Z[i] += rho*(t - s);
    acc += s;
  }
  atomicAdd(&sumS[b*D_+d], acc);
  __syncthreads();
  // transposed write: Et[b][d0+d_loc][n0+n_loc]
  const long EtBase = ((long)b*D_ + d0)*N_ + n0;
#pragma unroll
  for (int j=0;j<64;j++){
    int flat = j*256 + tid;
    int n_loc = flat & 63, d_loc = flat >> 6;
    Et[EtBase + (long)d_loc*N_ + n_loc] = tile[n_loc][d_loc];
  }
}

// ---------------- phase 8a: log_mu row update + z1 ----------------
__global__ __launch_bounds__(256)
void rowMu_kernel(float* __restrict__ logMu, float* __restrict__ Z1,
                  const float* __restrict__ p0, const float* __restrict__ sumT,
                  const float* __restrict__ a2p, const float* __restrict__ rhop, int it)
{
  __shared__ float sm[4];
  const int bn = blockIdx.x;
  const int b = bn >> 10;
  const long base = (long)bn * D_;
  const float a2 = a2p[it], rho = rhop[it];
  const float inv = 1.f/(rho+a2);
  const int d0 = threadIdx.x, d1 = d0+256;
  const long i0 = base + d0, i1 = base + d1;
  float y0 = (rho*logMu[i0] + a2*logf(p0[b*D_+d0]) - Z1[i0])*inv;
  float y1 = (rho*logMu[i1] + a2*logf(p0[b*D_+d1]) - Z1[i1])*inv;
  float M = blockMax(fmaxf(y0,y1), sm);
  float S = blockSum(expf(y0-M)+expf(y1-M), sm);
  float lse = M + logf(S);
  float st = sumT[bn];
  float lm0 = y0 - lse, lm1 = y1 - lse;
  logMu[i0]=lm0; logMu[i1]=lm1;
  Z1[i0] += rho*(expf(lm0) - st);
  Z1[i1] += rho*(expf(lm1) - st);
}

// ---------------- phase 8b: log_eta col pass 1 (y -> Ybuf, online-LSE partials) ----------------
__global__ __launch_bounds__(256)
void colEta1_kernel(const float* __restrict__ logEta, const float* __restrict__ q0,
                    const float* __restrict__ Z2, float* __restrict__ Ybuf,
                    float* __restrict__ pMax, float* __restrict__ pSum,
                    const float* __restrict__ a3p, const float* __restrict__ rhop, int it)
{
  const int d = blockIdx.x*256 + threadIdx.x;
  const int ch = blockIdx.y, b = blockIdx.z;
  const float a3 = a3p[it], rho = rhop[it];
  const float inv = 1.f/(rho+a3);
  long i = (long)b*N_*D_ + (long)(ch*CHUNK)*D_ + d;
  float m = -INFINITY, s = 0.f;
  for (int n=0;n<CHUNK;n++, i+=D_){
    int gn = ch*CHUNK + n;
    float lq0 = logf(q0[b*N_+gn] + EPSF);
    float yv = (rho*logEta[i] + a3*lq0 - Z2[i])*inv;
    Ybuf[i] = yv;
    float mn = fmaxf(m,yv);
    s = s*expf(m-mn) + expf(yv-mn);
    m = mn;
  }
  long pi = ((long)(b*D_+d))*CH + ch;
  pMax[pi]=m; pSum[pi]=s;
}

// ---------------- phase 8b cont: log_eta update + z2 ----------------
__global__ __launch_bounds__(256)
void colEta2_kernel(const float* __restrict__ Ybuf, float* __restrict__ logEta,
                    float* __restrict__ Z2, const float* __restrict__ Mcol,
                    const float* __restrict__ sumS,
                    const float* __restrict__ rhop, int it)
{
  const int d = blockIdx.x*256 + threadIdx.x;
  const int ch = blockIdx.y, b = blockIdx.z;
  const float rho = rhop[it];
  const float lseC = Mcol[b*D_+d];
  const float ss = sumS[b*D_+d];
  long i = (long)b*N_*D_ + (long)(ch*CHUNK)*D_ + d;
  for (int n=0;n<CHUNK;n++, i+=D_){
    float le = Ybuf[i] - lseC;
    logEta[i] = le;
    Z2[i] += rho*(expf(le) - ss);
  }
}

__global__ __launch_bounds__(256)
void final_kernel(float* __restrict__ E, const float* __restrict__ maskp)
{
  long i = (long)blockIdx.x*256 + threadIdx.x;
  long bn = i >> 9;
  E[i] = E[i]*maskp[bn];
}

// ---------------- launch ----------------
extern "C" void kernel_launch(void* const* d_in, const int* in_sizes, int n_in,
                              void* d_out, int out_size, void* d_ws, size_t ws_size,
                              hipStream_t stream)
{
  const float* x    = (const float*)d_in[0];
  const float* c1   = (const float*)d_in[1];
  const float* c2   = (const float*)d_in[2];
  const float* p0   = (const float*)d_in[3];
  const float* q0   = (const float*)d_in[4];
  const float* a0   = (const float*)d_in[5];
  const float* a1   = (const float*)d_in[6];
  const float* a2   = (const float*)d_in[7];
  const float* a3   = (const float*)d_in[8];
  const float* rho  = (const float*)d_in[9];
  const float* mask = (const float*)d_in[10];

  const size_t BND = (size_t)B_*N_*D_;           // 4,194,304
  float* w = (float*)d_ws;
  float* logS   = w + 0*BND;
  float* Z      = w + 1*BND;
  float* logMu  = w + 2*BND;
  float* logEta = w + 3*BND;
  float* Z1     = w + 4*BND;
  float* Z2     = w + 5*BND;
  float* P2     = w + 6*BND;                     // GEMM2 out -> colS1 y' -> eta Ybuf
  u16*  EtA  = (u16*)(w + 7*BND);                // bf16 [B][D][N]  (exp(log·)^T)
  u16*  T1b  = EtA + BND;                        // bf16 [B][N][D]  (c2 @ exp(·))
  u16*  c1t  = T1b + BND;                        // bf16 [B][D][D]  (c1 transposed)
  float* small = (float*)(c1t + (size_t)B_*D_*D_);
  float* sumT = small;                           // B*N
  float* sumS = sumT + B_*N_;                    // B*D
  float* Mcol = sumS + B_*D_;                    // B*D
  float* pMax = Mcol + B_*D_;                    // B*D*CH
  float* pSum = pMax + (size_t)B_*D_*CH;
  float* E    = (float*)d_out;                   // exp(logT), masked at the end

  dim3 blk(256);
  const int gBND = (int)(BND/256);               // 16384
  dim3 gT1(16, 8, B_);                           // tconv E: N/64, D/64, B
  dim3 gTc(8, 8, B_);                            // tconv c1: D/64, D/64, B
  dim3 gG(8, 8, B_);                             // gemm: M/128, Nout/64, B  -> 512 blocks
  dim3 gCol(D_/256, CH, B_);                     // (2,16,8)

  const long sC2 = (long)N_*N_, sND = (long)N_*D_, sC1 = (long)D_*D_, sDN = (long)D_*N_;

  init_kernel<<<gBND, blk, 0, stream>>>(logS, Z, logMu, logEta, Z1, Z2, p0, q0);
  initEt_kernel<<<gBND, blk, 0, stream>>>(EtA, p0, q0);
  tconv_kernel<<<gTc, blk, 0, stream>>>(c1, c1t, D_, D_);   // c1t = c1^T bf16

  for (int it=0; it<4; ++it) {
    // ---- log_t update: tmp2 = c2 @ exp(logS) @ c1 ----
    gemm_mfma<1024,1,1><<<gG, blk, 0, stream>>>(c2, nullptr, EtA, T1b, sC2, sDN, sND, D_);
    gemm_mfma< 512,0,0><<<gG, blk, 0, stream>>>(nullptr, T1b, c1t, P2, sND, sC1, sND, D_);
    rowA_kernel<<<B_*N_, blk, 0, stream>>>(x, P2, Z, logS, logMu, E, sumT, mask, a0, rho, it);
    // ---- log_s update: tmp2 = c2 @ exp(logT) @ c1 ----
    tconv_kernel<<<gT1, blk, 0, stream>>>(E, EtA, N_, D_);
    gemm_mfma<1024,1,1><<<gG, blk, 0, stream>>>(c2, nullptr, EtA, T1b, sC2, sDN, sND, D_);
    gemm_mfma< 512,0,0><<<gG, blk, 0, stream>>>(nullptr, T1b, c1t, P2, sND, sC1, sND, D_);
    colS1_kernel<<<gCol, blk, 0, stream>>>(P2, Z, E, pMax, pSum, a0, a1, rho, it);
    colCombine_kernel<<<B_*D_/256, blk, 0, stream>>>(pMax, pSum, Mcol, sumS, 1);
    colS2_kernel<<<gCol, blk, 0, stream>>>(P2, E, logS, Z, logEta, Mcol, sumS, mask, EtA, rho, it);
    // ---- marginals ----
    rowMu_kernel<<<B_*N_, blk, 0, stream>>>(logMu, Z1, p0, sumT, a2, rho, it);
    colEta1_kernel<<<gCol, blk, 0, stream>>>(logEta, q0, Z2, P2, pMax, pSum, a3, rho, it);
    colCombine_kernel<<<B_*D_/256, blk, 0, stream>>>(pMax, pSum, Mcol, sumS, 0);
    colEta2_kernel<<<gCol, blk, 0, stream>>>(P2, logEta, Z2, Mcol, sumS, rho, it);
  }
  final_kernel<<<gBND, blk, 0, stream>>>(E, mask);
}

// Round 7
// 760.860 us; speedup vs baseline: 2.6801x; 1.0837x over previous
//
#include <hip/hip_runtime.h>
#include <math.h>

#define B_ 8
#define N_ 1024
#define D_ 512
#define CH 32
#define CHUNK (N_/CH)   /* 32 rows per column-chunk */
#define EPSF 1e-8f

typedef unsigned short u16;
typedef __attribute__((ext_vector_type(8))) short bf16x8;
typedef __attribute__((ext_vector_type(4))) float f32x4;

static __device__ __forceinline__ u16 f2bf(float f){
  unsigned int u = __builtin_bit_cast(unsigned int, f);
  u = (u + 0x7FFFu + ((u >> 16) & 1u)) >> 16;
  return (u16)u;
}

// ---------------- reduction helpers (256-thread blocks = 4 waves) ----------------
static __device__ __forceinline__ float wredMax(float v){
#pragma unroll
  for (int o=32;o>=1;o>>=1) v = fmaxf(v, __shfl_xor(v,o,64));
  return v;
}
static __device__ __forceinline__ float wredSum(float v){
#pragma unroll
  for (int o=32;o>=1;o>>=1) v += __shfl_xor(v,o,64);
  return v;
}
static __device__ __forceinline__ float blockMax(float v, float* sm){
  v = wredMax(v);
  int w = threadIdx.x>>6, l = threadIdx.x&63;
  if (l==0) sm[w]=v;
  __syncthreads();
  float r = fmaxf(fmaxf(sm[0],sm[1]),fmaxf(sm[2],sm[3]));
  __syncthreads();
  return r;
}
static __device__ __forceinline__ float blockSum(float v, float* sm){
  v = wredSum(v);
  int w = threadIdx.x>>6, l = threadIdx.x&63;
  if (l==0) sm[w]=v;
  __syncthreads();
  float r = (sm[0]+sm[1])+(sm[2]+sm[3]);
  __syncthreads();
  return r;
}

// ---------------- init: materialize state as (B,N,D) ----------------
__global__ __launch_bounds__(256)
void init_kernel(float* __restrict__ logS,
                 float* __restrict__ Z, float* __restrict__ logMu,
                 float* __restrict__ logEta, float* __restrict__ Z1,
                 float* __restrict__ Z2,
                 const float* __restrict__ p0, const float* __restrict__ q0)
{
  long i = (long)blockIdx.x*256 + threadIdx.x;
  int d  = (int)(i & (D_-1));
  long bn = i >> 9;               // i / D_
  int b  = (int)(bn >> 10);       // bn / N_
  float p = p0[b*D_ + d];
  float q = q0[bn];
  logS[i] = logf(q*p + EPSF);
  Z[i] = 0.f;
  logMu[i]  = logf(p);
  logEta[i] = logf(q + EPSF);
  Z1[i] = 0.f;
  Z2[i] = 0.f;
}

// initEt: EtA[b][d][n] = bf16(q0[b][n]*p0[b][d] + eps)  (= exp(logS)^T for iter 0)
__global__ __launch_bounds__(256)
void initEt_kernel(u16* __restrict__ Et, const float* __restrict__ p0,
                   const float* __restrict__ q0)
{
  long i = (long)blockIdx.x*256 + threadIdx.x;   // over B*D*N
  int n = (int)(i & (N_-1));
  long bd = i >> 10;
  int d = (int)(bd & (D_-1));
  int b = (int)(bd >> 9);
  Et[i] = f2bf(p0[b*D_+d]*q0[b*N_+n] + EPSF);
}

// ---------------- plain fp32 -> bf16 convert (vectorized x4) ----------------
__global__ __launch_bounds__(256)
void conv_kernel(const float* __restrict__ src, u16* __restrict__ dst)
{
  long i = (long)blockIdx.x*256 + threadIdx.x;
  float4 v = ((const float4*)src)[i];
  ushort4 u;
  u.x=f2bf(v.x); u.y=f2bf(v.y); u.z=f2bf(v.z); u.w=f2bf(v.w);
  ((ushort4*)dst)[i] = u;
}

// ---------------- transpose-convert fp32 [R][C] -> bf16 [C][R], per batch ----------------
__global__ __launch_bounds__(256)
void tconv_kernel(const float* __restrict__ src, u16* __restrict__ dst, int R, int Ccols)
{
  __shared__ float tile[64][65];
  const int b = blockIdx.z;
  const long bb = (long)b*R*Ccols;
  const int r0 = blockIdx.x*64, c0 = blockIdx.y*64;
  const int c = threadIdx.x & 63, rr = threadIdx.x >> 6;
#pragma unroll
  for (int i=0;i<16;i++){
    int r = i*4 + rr;
    tile[r][c] = src[bb + (long)(r0+r)*Ccols + c0 + c];
  }
  __syncthreads();
#pragma unroll
  for (int i=0;i<16;i++){
    int r = i*4 + rr;
    dst[bb + (long)(c0+r)*R + r0 + c] = f2bf(tile[c][r]);
  }
}

// ---------------- bf16 MFMA GEMM: C[M][Nc] = A[M][K] * Bt[Nc][K]^T, batched ----------------
// 128x64 tile, BK=64, 256 threads = 4 waves (2x2), each wave 64x32 (acc[4][2]).
// LDS rows padded to 72 bf16 (144B). Register-prefetch of next K-step hides HBM latency.
template<int K, int A_FP32, int OUT_BF16>
__global__ __launch_bounds__(256)
void gemm_mfma(const float* __restrict__ Af, const u16* __restrict__ Ab,
               const u16* __restrict__ Btb, void* __restrict__ Cp,
               long sA, long sB, long sC, int ldc)
{
  __shared__ __attribute__((aligned(16))) u16 As[128*72];
  __shared__ __attribute__((aligned(16))) u16 Bs[64*72];
  const int t = threadIdx.x;
  const int b = blockIdx.z;
  const int row0 = blockIdx.x*128, col0 = blockIdx.y*64;
  const int w = t>>6, l = t&63, lr = l&15, lg = l>>4;
  const int wm = w>>1, wn = w&1;

  f32x4 acc[4][2];
#pragma unroll
  for (int m=0;m<4;m++)
#pragma unroll
    for (int n=0;n<2;n++) acc[m][n] = (f32x4){0.f,0.f,0.f,0.f};

  const float* Afb = Af ? (Af + (long)b*sA + (long)row0*K) : nullptr;
  const u16*  Abb = Ab ? (Ab + (long)b*sA + (long)row0*K) : nullptr;
  const u16*  Bbb = Btb + (long)b*sB + (long)col0*K;

  float4 pa[8];
  bf16x8 qa[4];
  bf16x8 qb[2];

  // ---- preload K-step 0 ----
  if constexpr (A_FP32) {
#pragma unroll
    for (int i=0;i<8;i++){ int g=i*256+t; int r=g>>4, c4=g&15;
      pa[i] = *(const float4*)(Afb + (long)r*K + c4*4); }
  } else {
#pragma unroll
    for (int i=0;i<4;i++){ int g=i*256+t; int r=g>>3, j=g&7;
      qa[i] = *(const bf16x8*)(Abb + (long)r*K + j*8); }
  }
#pragma unroll
  for (int i=0;i<2;i++){ int g=i*256+t; int r=g>>3, j=g&7;
    qb[i] = *(const bf16x8*)(Bbb + (long)r*K + j*8); }

  for (int k0 = 0; k0 < K; k0 += 64) {
    __syncthreads();
    // ---- regs -> LDS ----
    if constexpr (A_FP32) {
#pragma unroll
      for (int i=0;i<8;i++){ int g=i*256+t; int r=g>>4, c4=g&15;
        ushort4 u;
        u.x=f2bf(pa[i].x); u.y=f2bf(pa[i].y); u.z=f2bf(pa[i].z); u.w=f2bf(pa[i].w);
        *(ushort4*)&As[r*72 + c4*4] = u; }
    } else {
#pragma unroll
      for (int i=0;i<4;i++){ int g=i*256+t; int r=g>>3, j=g&7;
        *(bf16x8*)&As[r*72 + j*8] = qa[i]; }
    }
#pragma unroll
    for (int i=0;i<2;i++){ int g=i*256+t; int r=g>>3, j=g&7;
      *(bf16x8*)&Bs[r*72 + j*8] = qb[i]; }
    __syncthreads();
    // ---- issue next K-step's loads (hide under MFMA) ----
    if (k0 + 64 < K) {
      int kn = k0 + 64;
      if constexpr (A_FP32) {
#pragma unroll
        for (int i=0;i<8;i++){ int g=i*256+t; int r=g>>4, c4=g&15;
          pa[i] = *(const float4*)(Afb + (long)r*K + kn + c4*4); }
      } else {
#pragma unroll
        for (int i=0;i<4;i++){ int g=i*256+t; int r=g>>3, j=g&7;
          qa[i] = *(const bf16x8*)(Abb + (long)r*K + kn + j*8); }
      }
#pragma unroll
      for (int i=0;i<2;i++){ int g=i*256+t; int r=g>>3, j=g&7;
        qb[i] = *(const bf16x8*)(Bbb + (long)r*K + kn + j*8); }
    }
    // ---- compute ----
#pragma unroll
    for (int kk=0;kk<2;kk++){
      bf16x8 afr[4], bfr[2];
#pragma unroll
      for (int m=0;m<4;m++)
        afr[m] = *(const bf16x8*)&As[(wm*64 + m*16 + lr)*72 + kk*32 + lg*8];
#pragma unroll
      for (int n=0;n<2;n++)
        bfr[n] = *(const bf16x8*)&Bs[(wn*32 + n*16 + lr)*72 + kk*32 + lg*8];
#pragma unroll
      for (int m=0;m<4;m++)
#pragma unroll
        for (int n=0;n<2;n++)
          acc[m][n] = __builtin_amdgcn_mfma_f32_16x16x32_bf16(afr[m], bfr[n], acc[m][n], 0, 0, 0);
    }
  }

  // epilogue: D frag mapping col=lane&15, row=(lane>>4)*4+reg  [m89-verified]
  if constexpr (OUT_BF16) {
    u16* C = (u16*)Cp + (long)b*sC;
#pragma unroll
    for (int m=0;m<4;m++)
#pragma unroll
      for (int n=0;n<2;n++){
        int grow = row0 + wm*64 + m*16 + lg*4;
        int gcol = col0 + wn*32 + n*16 + lr;
#pragma unroll
        for (int r4=0;r4<4;r4++)
          C[(long)(grow+r4)*ldc + gcol] = f2bf(acc[m][n][r4]);
      }
  } else {
    float* C = (float*)Cp + (long)b*sC;
#pragma unroll
    for (int m=0;m<4;m++)
#pragma unroll
      for (int n=0;n<2;n++){
        int grow = row0 + wm*64 + m*16 + lg*4;
        int gcol = col0 + wn*32 + n*16 + lr;
#pragma unroll
        for (int r4=0;r4<4;r4++)
          C[(long)(grow+r4)*ldc + gcol] = acc[m][n][r4];
      }
  }
}

// ---------------- fused: row LSE over D (logT, E, sumT) + log_mu/z1 update ----------------
__global__ __launch_bounds__(256)
void rowAMu_kernel(const float* __restrict__ x, const float* __restrict__ P2,
                   const float* __restrict__ Z, const float* __restrict__ logS,
                   float* __restrict__ logMu, float* __restrict__ Z1,
                   float* __restrict__ E,
                   const float* __restrict__ p0, const float* __restrict__ maskp,
                   const float* __restrict__ a0p, const float* __restrict__ a2p,
                   const float* __restrict__ rhop, int it)
{
  __shared__ float sm[4];
  const int bn = blockIdx.x;
  const int b = bn >> 10;
  const long base = (long)bn * D_;
  const float a0 = a0p[it], a2 = a2p[it], rho = rhop[it];
  const float inv_rho = 1.f/rho;
  const int d0 = threadIdx.x, d1 = d0 + 256;
  const long i0 = base + d0, i1 = base + d1;
  float lm0 = logMu[i0], lm1 = logMu[i1];
  float y0 = (x[i0] + a0*P2[i0] - Z[i0])*inv_rho + logS[i0];
  float y1 = (x[i1] + a0*P2[i1] - Z[i1])*inv_rho + logS[i1];
  float M = blockMax(fmaxf(y0,y1), sm);
  float S = blockSum(expf(y0-M)+expf(y1-M), sm);
  float lse = M + logf(S);
  float msk = maskp[bn];
  float e0 = expf(lm0 - lse + y0), e1 = expf(lm1 - lse + y1);
  E[i0]=e0; E[i1]=e1;
  float TS = blockSum((e0+e1)*msk, sm);     // sum(t) over the row (masked)
  // ---- fused log_mu + z1 update (row-local; no other kernel touches logMu/Z1) ----
  const float inv2 = 1.f/(rho+a2);
  float z10 = Z1[i0], z11 = Z1[i1];
  float ym0 = (rho*lm0 + a2*logf(p0[b*D_+d0]) - z10)*inv2;
  float ym1 = (rho*lm1 + a2*logf(p0[b*D_+d1]) - z11)*inv2;
  float M2 = blockMax(fmaxf(ym0,ym1), sm);
  float S2 = blockSum(expf(ym0-M2)+expf(ym1-M2), sm);
  float lse2 = M2 + logf(S2);
  float lmn0 = ym0 - lse2, lmn1 = ym1 - lse2;
  logMu[i0]=lmn0; logMu[i1]=lmn1;
  Z1[i0] = z10 + rho*(expf(lmn0) - TS);
  Z1[i1] = z11 + rho*(expf(lmn1) - TS);
}

// ---------------- col pass 1: y' = (Z + a0*P2 + rho*log(E))/(a1+rho) -> P2; online-LSE partials ----------------
__global__ __launch_bounds__(256)
void colS1_kernel(float* __restrict__ P2, const float* __restrict__ Z,
                  const float* __restrict__ E,
                  float* __restrict__ pMax, float* __restrict__ pSum,
                  const float* __restrict__ a0p, const float* __restrict__ a1p,
                  const float* __restrict__ rhop, int it)
{
  const int d = blockIdx.x*256 + threadIdx.x;
  const int ch = blockIdx.y, b = blockIdx.z;
  const float a0=a0p[it], rho=rhop[it];
  const float inv = 1.f/(a1p[it]+rho);
  long i = (long)b*N_*D_ + (long)(ch*CHUNK)*D_ + d;
  float m = -INFINITY, s = 0.f;
  for (int n=0;n<CHUNK;n++, i+=D_){
    float lt = logf(E[i] + 1e-37f);
    float yv = (Z[i] + a0*P2[i] + rho*lt)*inv;
    P2[i] = yv;
    float mn = fmaxf(m,yv);
    s = s*expf(m-mn) + expf(yv-mn);
    m = mn;
  }
  long pi = ((long)(b*D_+d))*CH + ch;
  pMax[pi]=m; pSum[pi]=s;
}

// ---------------- fused col pass 2: inline combine, logS/s/t/Z update, sSum,
//                  Et = bf16(exp(logS))^T, AND eta pass-1 (yv2 -> P2, partials) ----------------
__global__ __launch_bounds__(256)
void colS2E1_kernel(float* __restrict__ P2, const float* __restrict__ E,
                    float* __restrict__ logS, float* __restrict__ Z,
                    const float* __restrict__ logEta,
                    const float* __restrict__ pMax, const float* __restrict__ pSum,
                    float* __restrict__ sSum, float* __restrict__ pMax2,
                    float* __restrict__ pSum2,
                    const float* __restrict__ maskp, const float* __restrict__ q0,
                    const float* __restrict__ Z2, u16* __restrict__ Et,
                    const float* __restrict__ a3p, const float* __restrict__ rhop, int it)
{
  __shared__ u16 tile[CHUNK][258];
  const int tid = threadIdx.x;
  const int d0 = blockIdx.x*256;
  const int d = d0 + tid;
  const int ch = blockIdx.y, b = blockIdx.z;
  const int n0 = ch*CHUNK;
  const float rho = rhop[it], a3 = a3p[it];
  const float inv3 = 1.f/(rho+a3);
  const long bd = (long)(b*D_+d);
  // inline combine of colS1 partials -> column LSE
  float M = -INFINITY;
#pragma unroll
  for (int c=0;c<CH;c++) M = fmaxf(M, pMax[bd*CH+c]);
  float S = 0.f;
#pragma unroll
  for (int c=0;c<CH;c++) S += pSum[bd*CH+c]*expf(pMax[bd*CH+c]-M);
  const float lseC = M + logf(S);
  long i = (long)b*N_*D_ + (long)n0*D_ + d;
  float acc = 0.f;
  float m2 = -INFINITY, s2 = 0.f;
  for (int n=0;n<CHUNK;n++, i+=D_){
    int gn = n0 + n;
    float msk = maskp[b*N_+gn];
    float le_old = logEta[i];
    float ls = le_old - lseC + P2[i];
    logS[i] = ls;
    float es = expf(ls);
    tile[n][tid] = f2bf(es);
    float s = es*msk;
    float t = E[i]*msk;
    Z[i] += rho*(t - s);
    acc += s;
    // eta pass-1 (uses OLD logEta / OLD Z2, per reference ordering)
    float lq0 = logf(q0[b*N_+gn] + EPSF);
    float yv2 = (rho*le_old + a3*lq0 - Z2[i])*inv3;
    P2[i] = yv2;
    float mn = fmaxf(m2,yv2);
    s2 = s2*expf(m2-mn) + expf(yv2-mn);
    m2 = mn;
  }
  sSum[bd*CH+ch]  = acc;
  pMax2[bd*CH+ch] = m2;
  pSum2[bd*CH+ch] = s2;
  __syncthreads();
  // transposed Et write: Et[b][d0+d_loc][n0+n_loc]
  const long EtBase = ((long)b*D_ + d0)*N_ + n0;
#pragma unroll
  for (int j=0;j<CHUNK;j++){
    int flat = j*256 + tid;
    int n_loc = flat & (CHUNK-1), d_loc = flat >> 5;
    Et[EtBase + (long)d_loc*N_ + n_loc] = tile[n_loc][d_loc];
  }
}

// ---------------- eta pass 2: inline combine + log_eta / z2 update ----------------
__global__ __launch_bounds__(256)
void colEta2_kernel(const float* __restrict__ Ybuf, float* __restrict__ logEta,
                    float* __restrict__ Z2,
                    const float* __restrict__ pMax2, const float* __restrict__ pSum2,
                    const float* __restrict__ sSum,
                    const float* __restrict__ rhop, int it)
{
  const int d = blockIdx.x*256 + threadIdx.x;
  const int ch = blockIdx.y, b = blockIdx.z;
  const float rho = rhop[it];
  const long bd = (long)(b*D_+d);
  float M = -INFINITY;
#pragma unroll
  for (int c=0;c<CH;c++) M = fmaxf(M, pMax2[bd*CH+c]);
  float S = 0.f;
#pragma unroll
  for (int c=0;c<CH;c++) S += pSum2[bd*CH+c]*expf(pMax2[bd*CH+c]-M);
  const float lseC = M + logf(S);
  float ss = 0.f;
#pragma unroll
  for (int c=0;c<CH;c++) ss += sSum[bd*CH+c];
  long i = (long)b*N_*D_ + (long)(ch*CHUNK)*D_ + d;
  for (int n=0;n<CHUNK;n++, i+=D_){
    float le = Ybuf[i] - lseC;
    logEta[i] = le;
    Z2[i] += rho*(expf(le) - ss);
  }
}

__global__ __launch_bounds__(256)
void final_kernel(float* __restrict__ E, const float* __restrict__ maskp)
{
  long i = (long)blockIdx.x*256 + threadIdx.x;
  long bn = i >> 9;
  E[i] = E[i]*maskp[bn];
}

// ---------------- launch ----------------
extern "C" void kernel_launch(void* const* d_in, const int* in_sizes, int n_in,
                              void* d_out, int out_size, void* d_ws, size_t ws_size,
                              hipStream_t stream)
{
  const float* x    = (const float*)d_in[0];
  const float* c1   = (const float*)d_in[1];
  const float* c2   = (const float*)d_in[2];
  const float* p0   = (const float*)d_in[3];
  const float* q0   = (const float*)d_in[4];
  const float* a0   = (const float*)d_in[5];
  const float* a1   = (const float*)d_in[6];
  const float* a2   = (const float*)d_in[7];
  const float* a3   = (const float*)d_in[8];
  const float* rho  = (const float*)d_in[9];
  const float* mask = (const float*)d_in[10];

  const size_t BND = (size_t)B_*N_*D_;           // 4,194,304 elements
  char* wb = (char*)d_ws;
  float* logS   = (float*)(wb);                  // 7 f32 (B,N,D) buffers
  float* Z      = logS   + BND;
  float* logMu  = Z      + BND;
  float* logEta = logMu  + BND;
  float* Z1     = logEta + BND;
  float* Z2     = Z1     + BND;
  float* P2     = Z2     + BND;                  // GEMM2 out -> colS1 y' -> eta Ybuf
  u16*  EtA  = (u16*)(P2 + BND);                 // bf16 [B][D][N]  (exp(log·)^T)
  u16*  T1b  = EtA + BND;                        // bf16 [B][N][D]  (c2 @ exp(·))
  u16*  c1t  = T1b + BND;                        // bf16 [B][D][D]  (c1 transposed)
  float* pMax  = (float*)(c1t + (size_t)B_*D_*D_);
  const size_t PART = (size_t)B_*D_*CH;          // 131072
  float* pSum  = pMax  + PART;
  float* pMax2 = pSum  + PART;
  float* pSum2 = pMax2 + PART;
  float* sSum  = pSum2 + PART;
  u16*  c2b  = (u16*)(sSum + PART);              // bf16 [B][N][N] (optional, guarded)
  const size_t need_c2b = (size_t)((char*)(c2b + (size_t)B_*N_*N_) - wb);
  const bool use_c2b = (ws_size >= need_c2b);
  float* E    = (float*)d_out;                   // exp(logT), masked at the end

  dim3 blk(256);
  const int gBND = (int)(BND/256);               // 16384
  dim3 gT1(16, 8, B_);                           // tconv E: N/64, D/64, B
  dim3 gTc(8, 8, B_);                            // tconv c1: D/64, D/64, B
  dim3 gG(8, 8, B_);                             // gemm: M/128, Nout/64, B -> 512 blocks
  dim3 gCol(D_/256, CH, B_);                     // (2,32,8) -> 512 blocks

  const long sC2 = (long)N_*N_, sND = (long)N_*D_, sC1 = (long)D_*D_, sDN = (long)D_*N_;

  init_kernel<<<gBND, blk, 0, stream>>>(logS, Z, logMu, logEta, Z1, Z2, p0, q0);
  initEt_kernel<<<gBND, blk, 0, stream>>>(EtA, p0, q0);
  tconv_kernel<<<gTc, blk, 0, stream>>>(c1, c1t, D_, D_);         // c1t = c1^T bf16
  if (use_c2b)
    conv_kernel<<<(int)((size_t)B_*N_*N_/4/256), blk, 0, stream>>>(c2, c2b);

  for (int it=0; it<4; ++it) {
    // ---- log_t update: tmp2 = c2 @ exp(logS) @ c1 ----
    if (use_c2b)
      gemm_mfma<1024,0,1><<<gG, blk, 0, stream>>>(nullptr, c2b, EtA, T1b, sC2, sDN, sND, D_);
    else
      gemm_mfma<1024,1,1><<<gG, blk, 0, stream>>>(c2, nullptr, EtA, T1b, sC2, sDN, sND, D_);
    gemm_mfma< 512,0,0><<<gG, blk, 0, stream>>>(nullptr, T1b, c1t, P2, sND, sC1, sND, D_);
    rowAMu_kernel<<<B_*N_, blk, 0, stream>>>(x, P2, Z, logS, logMu, Z1, E, p0, mask, a0, a2, rho, it);
    // ---- log_s update: tmp2 = c2 @ exp(logT) @ c1 ----
    tconv_kernel<<<gT1, blk, 0, stream>>>(E, EtA, N_, D_);
    if (use_c2b)
      gemm_mfma<1024,0,1><<<gG, blk, 0, stream>>>(nullptr, c2b, EtA, T1b, sC2, sDN, sND, D_);
    else
      gemm_mfma<1024,1,1><<<gG, blk, 0, stream>>>(c2, nullptr, EtA, T1b, sC2, sDN, sND, D_);
    gemm_mfma< 512,0,0><<<gG, blk, 0, stream>>>(nullptr, T1b, c1t, P2, sND, sC1, sND, D_);
    colS1_kernel<<<gCol, blk, 0, stream>>>(P2, Z, E, pMax, pSum, a0, a1, rho, it);
    colS2E1_kernel<<<gCol, blk, 0, stream>>>(P2, E, logS, Z, logEta, pMax, pSum,
                                             sSum, pMax2, pSum2, mask, q0, Z2, EtA,
                                             a3, rho, it);
    colEta2_kernel<<<gCol, blk, 0, stream>>>(P2, logEta, Z2, pMax2, pSum2, sSum, rho, it);
  }
  final_kernel<<<gBND, blk, 0, stream>>>(E, mask);
}

// Round 8
// 599.710 us; speedup vs baseline: 3.4003x; 1.2687x over previous
//
#include <hip/hip_runtime.h>
#include <math.h>

#define B_ 8
#define N_ 1024
#define D_ 512
#define CH 32
#define CHUNK (N_/CH)   /* 32 rows per column-chunk */
#define EPSF 1e-8f

typedef unsigned short u16;
typedef __attribute__((ext_vector_type(8))) short bf16x8;
typedef __attribute__((ext_vector_type(4))) float f32x4;

static __device__ __forceinline__ u16 f2bf(float f){
  unsigned int u = __builtin_bit_cast(unsigned int, f);
  u = (u + 0x7FFFu + ((u >> 16) & 1u)) >> 16;
  return (u16)u;
}

// ---------------- reduction helpers (256-thread blocks = 4 waves) ----------------
static __device__ __forceinline__ float wredMax(float v){
#pragma unroll
  for (int o=32;o>=1;o>>=1) v = fmaxf(v, __shfl_xor(v,o,64));
  return v;
}
static __device__ __forceinline__ float wredSum(float v){
#pragma unroll
  for (int o=32;o>=1;o>>=1) v += __shfl_xor(v,o,64);
  return v;
}
static __device__ __forceinline__ float blockMax(float v, float* sm){
  v = wredMax(v);
  int w = threadIdx.x>>6, l = threadIdx.x&63;
  if (l==0) sm[w]=v;
  __syncthreads();
  float r = fmaxf(fmaxf(sm[0],sm[1]),fmaxf(sm[2],sm[3]));
  __syncthreads();
  return r;
}
static __device__ __forceinline__ float blockSum(float v, float* sm){
  v = wredSum(v);
  int w = threadIdx.x>>6, l = threadIdx.x&63;
  if (l==0) sm[w]=v;
  __syncthreads();
  float r = (sm[0]+sm[1])+(sm[2]+sm[3]);
  __syncthreads();
  return r;
}

// ---------------- init: logS/Z as (B,N,D); marginals as small vectors ----------------
__global__ __launch_bounds__(256)
void init_kernel(float* __restrict__ logS, float* __restrict__ Z,
                 const float* __restrict__ p0, const float* __restrict__ q0)
{
  long i = (long)blockIdx.x*256 + threadIdx.x;
  int d  = (int)(i & (D_-1));
  long bn = i >> 9;
  int b  = (int)(bn >> 10);
  logS[i] = logf(q0[bn]*p0[b*D_+d] + EPSF);
  Z[i] = 0.f;
}

// marginal state: M[d]=log_mu, u[d]=z1 d-part, Lv[n]=log_eta, p[n]=z2 n-part
__global__ __launch_bounds__(256)
void margInit_kernel(float* __restrict__ M, float* __restrict__ u,
                     float* __restrict__ Lv, float* __restrict__ p,
                     const float* __restrict__ p0, const float* __restrict__ q0)
{
  int b = blockIdx.x, t = threadIdx.x;
  for (int d = t; d < D_; d += 256){ M[b*D_+d] = logf(p0[b*D_+d]); u[b*D_+d] = 0.f; }
  for (int n = t; n < N_; n += 256){ Lv[b*N_+n] = logf(q0[b*N_+n] + EPSF); p[b*N_+n] = 0.f; }
}

// initEt: EtA[b][d][n] = bf16(q0[b][n]*p0[b][d] + eps)  (= exp(logS)^T for iter 0)
__global__ __launch_bounds__(256)
void initEt_kernel(u16* __restrict__ Et, const float* __restrict__ p0,
                   const float* __restrict__ q0)
{
  long i = (long)blockIdx.x*256 + threadIdx.x;   // over B*D*N
  int n = (int)(i & (N_-1));
  long bd = i >> 10;
  int d = (int)(bd & (D_-1));
  int b = (int)(bd >> 9);
  Et[i] = f2bf(p0[b*D_+d]*q0[b*N_+n] + EPSF);
}

// ---------------- plain fp32 -> bf16 convert (vectorized x4) ----------------
__global__ __launch_bounds__(256)
void conv_kernel(const float* __restrict__ src, u16* __restrict__ dst)
{
  long i = (long)blockIdx.x*256 + threadIdx.x;
  float4 v = ((const float4*)src)[i];
  ushort4 u;
  u.x=f2bf(v.x); u.y=f2bf(v.y); u.z=f2bf(v.z); u.w=f2bf(v.w);
  ((ushort4*)dst)[i] = u;
}

// ---------------- transpose-convert fp32 [R][C] -> bf16 [C][R], per batch ----------------
__global__ __launch_bounds__(256)
void tconv_kernel(const float* __restrict__ src, u16* __restrict__ dst, int R, int Ccols)
{
  __shared__ float tile[64][65];
  const int b = blockIdx.z;
  const long bb = (long)b*R*Ccols;
  const int r0 = blockIdx.x*64, c0 = blockIdx.y*64;
  const int c = threadIdx.x & 63, rr = threadIdx.x >> 6;
#pragma unroll
  for (int i=0;i<16;i++){
    int r = i*4 + rr;
    tile[r][c] = src[bb + (long)(r0+r)*Ccols + c0 + c];
  }
  __syncthreads();
#pragma unroll
  for (int i=0;i<16;i++){
    int r = i*4 + rr;
    dst[bb + (long)(c0+r)*R + r0 + c] = f2bf(tile[c][r]);
  }
}

// ---------------- bf16 MFMA GEMM: C[M][Nc] = A[M][K] * Bt[Nc][K]^T, batched ----------------
// 128x64 tile, BK=64, 256 threads = 4 waves (2x2), each wave 64x32 (acc[4][2]).
// LDS rows padded to 72 bf16 (144B). Register-prefetch of next K-step hides HBM latency.
template<int K, int OUT_BF16>
__global__ __launch_bounds__(256)
void gemm_mfma(const u16* __restrict__ Ab, const u16* __restrict__ Btb,
               void* __restrict__ Cp, long sA, long sB, long sC, int ldc)
{
  __shared__ __attribute__((aligned(16))) u16 As[128*72];
  __shared__ __attribute__((aligned(16))) u16 Bs[64*72];
  const int t = threadIdx.x;
  const int b = blockIdx.z;
  const int row0 = blockIdx.x*128, col0 = blockIdx.y*64;
  const int w = t>>6, l = t&63, lr = l&15, lg = l>>4;
  const int wm = w>>1, wn = w&1;

  f32x4 acc[4][2];
#pragma unroll
  for (int m=0;m<4;m++)
#pragma unroll
    for (int n=0;n<2;n++) acc[m][n] = (f32x4){0.f,0.f,0.f,0.f};

  const u16* Abb = Ab + (long)b*sA + (long)row0*K;
  const u16* Bbb = Btb + (long)b*sB + (long)col0*K;

  bf16x8 qa[4];
  bf16x8 qb[2];

  // ---- preload K-step 0 ----
#pragma unroll
  for (int i=0;i<4;i++){ int g=i*256+t; int r=g>>3, j=g&7;
    qa[i] = *(const bf16x8*)(Abb + (long)r*K + j*8); }
#pragma unroll
  for (int i=0;i<2;i++){ int g=i*256+t; int r=g>>3, j=g&7;
    qb[i] = *(const bf16x8*)(Bbb + (long)r*K + j*8); }

  for (int k0 = 0; k0 < K; k0 += 64) {
    __syncthreads();
#pragma unroll
    for (int i=0;i<4;i++){ int g=i*256+t; int r=g>>3, j=g&7;
      *(bf16x8*)&As[r*72 + j*8] = qa[i]; }
#pragma unroll
    for (int i=0;i<2;i++){ int g=i*256+t; int r=g>>3, j=g&7;
      *(bf16x8*)&Bs[r*72 + j*8] = qb[i]; }
    __syncthreads();
    // ---- issue next K-step's loads (hide under MFMA) ----
    if (k0 + 64 < K) {
      int kn = k0 + 64;
#pragma unroll
      for (int i=0;i<4;i++){ int g=i*256+t; int r=g>>3, j=g&7;
        qa[i] = *(const bf16x8*)(Abb + (long)r*K + kn + j*8); }
#pragma unroll
      for (int i=0;i<2;i++){ int g=i*256+t; int r=g>>3, j=g&7;
        qb[i] = *(const bf16x8*)(Bbb + (long)r*K + kn + j*8); }
    }
    // ---- compute ----
#pragma unroll
    for (int kk=0;kk<2;kk++){
      bf16x8 afr[4], bfr[2];
#pragma unroll
      for (int m=0;m<4;m++)
        afr[m] = *(const bf16x8*)&As[(wm*64 + m*16 + lr)*72 + kk*32 + lg*8];
#pragma unroll
      for (int n=0;n<2;n++)
        bfr[n] = *(const bf16x8*)&Bs[(wn*32 + n*16 + lr)*72 + kk*32 + lg*8];
#pragma unroll
      for (int m=0;m<4;m++)
#pragma unroll
        for (int n=0;n<2;n++)
          acc[m][n] = __builtin_amdgcn_mfma_f32_16x16x32_bf16(afr[m], bfr[n], acc[m][n], 0, 0, 0);
    }
  }

  // epilogue: D frag mapping col=lane&15, row=(lane>>4)*4+reg  [m89-verified]
  if constexpr (OUT_BF16) {
    u16* C = (u16*)Cp + (long)b*sC;
#pragma unroll
    for (int m=0;m<4;m++)
#pragma unroll
      for (int n=0;n<2;n++){
        int grow = row0 + wm*64 + m*16 + lg*4;
        int gcol = col0 + wn*32 + n*16 + lr;
#pragma unroll
        for (int r4=0;r4<4;r4++)
          C[(long)(grow+r4)*ldc + gcol] = f2bf(acc[m][n][r4]);
      }
  } else {
    float* C = (float*)Cp + (long)b*sC;
#pragma unroll
    for (int m=0;m<4;m++)
#pragma unroll
      for (int n=0;n<2;n++){
        int grow = row0 + wm*64 + m*16 + lg*4;
        int gcol = col0 + wn*32 + n*16 + lr;
#pragma unroll
        for (int r4=0;r4<4;r4++)
          C[(long)(grow+r4)*ldc + gcol] = acc[m][n][r4];
      }
  }
}

// ---------------- row LSE over D: E = exp(M[d] - lse(y) + y) ----------------
__global__ __launch_bounds__(256)
void rowA_kernel(const float* __restrict__ x, const float* __restrict__ P2,
                 const float* __restrict__ Z, const float* __restrict__ logS,
                 const float* __restrict__ M, float* __restrict__ E,
                 const float* __restrict__ a0p, const float* __restrict__ rhop, int it)
{
  __shared__ float sm[4];
  const int bn = blockIdx.x;
  const int b = bn >> 10;
  const long base = (long)bn * D_;
  const float a0 = a0p[it], rho = rhop[it];
  const float inv_rho = 1.f/rho;
  const int d0 = threadIdx.x, d1 = d0 + 256;
  const long i0 = base + d0, i1 = base + d1;
  float y0 = (x[i0] + a0*P2[i0] - Z[i0])*inv_rho + logS[i0];
  float y1 = (x[i1] + a0*P2[i1] - Z[i1])*inv_rho + logS[i1];
  float Mx = blockMax(fmaxf(y0,y1), sm);
  float S = blockSum(expf(y0-Mx)+expf(y1-Mx), sm);
  float lse = Mx + logf(S);
  E[i0] = expf(M[b*D_+d0] - lse + y0);
  E[i1] = expf(M[b*D_+d1] - lse + y1);
}

// ---------------- col pass 1: y' = (Z + a0*P2 + rho*log(E))/(a1+rho) -> P2; online-LSE partials ----------------
__global__ __launch_bounds__(256)
void colS1_kernel(float* __restrict__ P2, const float* __restrict__ Z,
                  const float* __restrict__ E,
                  float* __restrict__ pMax, float* __restrict__ pSum,
                  const float* __restrict__ a0p, const float* __restrict__ a1p,
                  const float* __restrict__ rhop, int it)
{
  const int d = blockIdx.x*256 + threadIdx.x;
  const int ch = blockIdx.y, b = blockIdx.z;
  const float a0=a0p[it], rho=rhop[it];
  const float inv = 1.f/(a1p[it]+rho);
  long i = (long)b*N_*D_ + (long)(ch*CHUNK)*D_ + d;
  float m = -INFINITY, s = 0.f;
  for (int n=0;n<CHUNK;n++, i+=D_){
    float lt = logf(E[i] + 1e-37f);
    float yv = (Z[i] + a0*P2[i] + rho*lt)*inv;
    P2[i] = yv;
    float mn = fmaxf(m,yv);
    s = s*expf(m-mn) + expf(yv-mn);
    m = mn;
  }
  long pi = ((long)(b*D_+d))*CH + ch;
  pMax[pi]=m; pSum[pi]=s;
}

// ---------------- col pass 2: inline combine; logS, Z update; Et = bf16(exp(logS))^T ----------------
__global__ __launch_bounds__(256)
void colS2_kernel(const float* __restrict__ Yp, const float* __restrict__ E,
                  float* __restrict__ logS, float* __restrict__ Z,
                  const float* __restrict__ Lv,
                  const float* __restrict__ pMax, const float* __restrict__ pSum,
                  const float* __restrict__ maskp, u16* __restrict__ Et,
                  const float* __restrict__ rhop, int it)
{
  __shared__ u16 tile[CHUNK][258];
  const int tid = threadIdx.x;
  const int d0 = blockIdx.x*256;
  const int d = d0 + tid;
  const int ch = blockIdx.y, b = blockIdx.z;
  const int n0 = ch*CHUNK;
  const float rho = rhop[it];
  const long bd = (long)(b*D_+d);
  float M = -INFINITY;
#pragma unroll
  for (int c=0;c<CH;c++) M = fmaxf(M, pMax[bd*CH+c]);
  float S = 0.f;
#pragma unroll
  for (int c=0;c<CH;c++) S += pSum[bd*CH+c]*expf(pMax[bd*CH+c]-M);
  const float lseC = M + logf(S);
  long i = (long)b*N_*D_ + (long)n0*D_ + d;
  for (int n=0;n<CHUNK;n++, i+=D_){
    int gn = n0 + n;
    float msk = maskp[b*N_+gn];
    float ls = Lv[b*N_+gn] - lseC + Yp[i];
    logS[i] = ls;
    float es = expf(ls);
    tile[n][tid] = f2bf(es);
    Z[i] += rho*msk*(E[i] - es);
  }
  __syncthreads();
  const long EtBase = ((long)b*D_ + d0)*N_ + n0;
#pragma unroll
  for (int j=0;j<CHUNK;j++){
    int flat = j*256 + tid;
    int n_loc = flat & (CHUNK-1), d_loc = flat >> 5;
    Et[EtBase + (long)d_loc*N_ + n_loc] = tile[n_loc][d_loc];
  }
}

// ---------------- marginal updates (tiny): M/u over D, Lv/p over N ----------------
__global__ __launch_bounds__(256)
void margUpd_kernel(float* __restrict__ M, float* __restrict__ u,
                    float* __restrict__ Lv, float* __restrict__ p,
                    const float* __restrict__ p0, const float* __restrict__ q0,
                    const float* __restrict__ a2p, const float* __restrict__ a3p,
                    const float* __restrict__ rhop, int it)
{
  __shared__ float sm[4];
  const int b = blockIdx.x;
  const float rho = rhop[it];
  if (blockIdx.y == 0) {
    const float a2 = a2p[it], inv = 1.f/(rho+a2);
    const int d0 = threadIdx.x, d1 = d0+256;
    float A0 = (rho*M[b*D_+d0] + a2*logf(p0[b*D_+d0]) - u[b*D_+d0])*inv;
    float A1 = (rho*M[b*D_+d1] + a2*logf(p0[b*D_+d1]) - u[b*D_+d1])*inv;
    float Mx = blockMax(fmaxf(A0,A1), sm);
    float Sx = blockSum(expf(A0-Mx)+expf(A1-Mx), sm);
    float lse = Mx + logf(Sx);
    float M0 = A0 - lse, M1 = A1 - lse;
    M[b*D_+d0]=M0; M[b*D_+d1]=M1;
    u[b*D_+d0] += rho*expf(M0);
    u[b*D_+d1] += rho*expf(M1);
  } else {
    const float a3 = a3p[it], inv = 1.f/(rho+a3);
    const int n = threadIdx.x;
    float y0 = (rho*Lv[b*N_+n]     + a3*logf(q0[b*N_+n]+EPSF)     - p[b*N_+n])*inv;
    float y1 = (rho*Lv[b*N_+n+256] + a3*logf(q0[b*N_+n+256]+EPSF) - p[b*N_+n+256])*inv;
    float y2 = (rho*Lv[b*N_+n+512] + a3*logf(q0[b*N_+n+512]+EPSF) - p[b*N_+n+512])*inv;
    float y3 = (rho*Lv[b*N_+n+768] + a3*logf(q0[b*N_+n+768]+EPSF) - p[b*N_+n+768])*inv;
    float Mx = blockMax(fmaxf(fmaxf(y0,y1),fmaxf(y2,y3)), sm);
    float Sx = blockSum(expf(y0-Mx)+expf(y1-Mx)+expf(y2-Mx)+expf(y3-Mx), sm);
    float lse = Mx + logf(Sx);
    float L0=y0-lse, L1=y1-lse, L2=y2-lse, L3=y3-lse;
    Lv[b*N_+n]=L0; Lv[b*N_+n+256]=L1; Lv[b*N_+n+512]=L2; Lv[b*N_+n+768]=L3;
    p[b*N_+n]     += rho*expf(L0);
    p[b*N_+n+256] += rho*expf(L1);
    p[b*N_+n+512] += rho*expf(L2);
    p[b*N_+n+768] += rho*expf(L3);
  }
}

__global__ __launch_bounds__(256)
void final_kernel(float* __restrict__ E, const float* __restrict__ maskp)
{
  long i = (long)blockIdx.x*256 + threadIdx.x;
  long bn = i >> 9;
  E[i] = E[i]*maskp[bn];
}

// ---------------- launch ----------------
extern "C" void kernel_launch(void* const* d_in, const int* in_sizes, int n_in,
                              void* d_out, int out_size, void* d_ws, size_t ws_size,
                              hipStream_t stream)
{
  const float* x    = (const float*)d_in[0];
  const float* c1   = (const float*)d_in[1];
  const float* c2   = (const float*)d_in[2];
  const float* p0   = (const float*)d_in[3];
  const float* q0   = (const float*)d_in[4];
  const float* a0   = (const float*)d_in[5];
  const float* a1   = (const float*)d_in[6];
  const float* a2   = (const float*)d_in[7];
  const float* a3   = (const float*)d_in[8];
  const float* rho  = (const float*)d_in[9];
  const float* mask = (const float*)d_in[10];

  const size_t BND = (size_t)B_*N_*D_;           // 4,194,304 elements
  char* wb = (char*)d_ws;
  float* logS = (float*)(wb);                    // 3 f32 (B,N,D) buffers
  float* Z    = logS + BND;
  float* P2   = Z    + BND;
  u16*  EtA = (u16*)(P2 + BND);                  // bf16 [B][D][N]
  u16*  T1b = EtA + BND;                         // bf16 [B][N][D]
  u16*  c1t = T1b + BND;                         // bf16 [B][D][D]
  u16*  c2b = c1t + (size_t)B_*D_*D_;            // bf16 [B][N][N]
  float* pMax = (float*)(c2b + (size_t)B_*N_*N_);
  const size_t PART = (size_t)B_*D_*CH;          // 131072
  float* pSum = pMax + PART;
  float* Mv   = pSum + PART;                     // B*D
  float* uv   = Mv + (size_t)B_*D_;              // B*D
  float* Lv   = uv + (size_t)B_*D_;              // B*N
  float* pv   = Lv + (size_t)B_*N_;              // B*N
  float* E    = (float*)d_out;                   // exp(log_t), masked at the end

  dim3 blk(256);
  const int gBND = (int)(BND/256);               // 16384
  dim3 gT1(16, 8, B_);                           // tconv E: N/64, D/64, B
  dim3 gTc(8, 8, B_);                            // tconv c1: D/64, D/64, B
  dim3 gG(8, 8, B_);                             // gemm: M/128, Nout/64, B -> 512 blocks
  dim3 gCol(D_/256, CH, B_);                     // (2,32,8) -> 512 blocks
  dim3 gMarg(B_, 2);

  const long sC2 = (long)N_*N_, sND = (long)N_*D_, sC1 = (long)D_*D_, sDN = (long)D_*N_;

  init_kernel<<<gBND, blk, 0, stream>>>(logS, Z, p0, q0);
  margInit_kernel<<<B_, blk, 0, stream>>>(Mv, uv, Lv, pv, p0, q0);
  initEt_kernel<<<gBND, blk, 0, stream>>>(EtA, p0, q0);
  tconv_kernel<<<gTc, blk, 0, stream>>>(c1, c1t, D_, D_);         // c1t = c1^T bf16
  conv_kernel<<<(int)((size_t)B_*N_*N_/4/256), blk, 0, stream>>>(c2, c2b);

  for (int it=0; it<4; ++it) {
    // ---- log_t update: tmp2 = c2 @ exp(logS) @ c1 ----
    gemm_mfma<1024,1><<<gG, blk, 0, stream>>>(c2b, EtA, T1b, sC2, sDN, sND, D_);
    gemm_mfma< 512,0><<<gG, blk, 0, stream>>>(T1b, c1t, P2, sND, sC1, sND, D_);
    rowA_kernel<<<B_*N_, blk, 0, stream>>>(x, P2, Z, logS, Mv, E, a0, rho, it);
    // ---- log_s update: tmp2 = c2 @ exp(logT) @ c1 ----
    tconv_kernel<<<gT1, blk, 0, stream>>>(E, EtA, N_, D_);
    gemm_mfma<1024,1><<<gG, blk, 0, stream>>>(c2b, EtA, T1b, sC2, sDN, sND, D_);
    gemm_mfma< 512,0><<<gG, blk, 0, stream>>>(T1b, c1t, P2, sND, sC1, sND, D_);
    colS1_kernel<<<gCol, blk, 0, stream>>>(P2, Z, E, pMax, pSum, a0, a1, rho, it);
    colS2_kernel<<<gCol, blk, 0, stream>>>(P2, E, logS, Z, Lv, pMax, pSum, mask, EtA, rho, it);
    // ---- marginal updates (small vectors) ----
    margUpd_kernel<<<gMarg, blk, 0, stream>>>(Mv, uv, Lv, pv, p0, q0, a2, a3, rho, it);
  }
  final_kernel<<<gBND, blk, 0, stream>>>(E, mask);
}

// Round 9
// 584.167 us; speedup vs baseline: 3.4908x; 1.0266x over previous
//
#include <hip/hip_runtime.h>
#include <math.h>

#define B_ 8
#define N_ 1024
#define D_ 512
#define CH 32
#define CHUNK (N_/CH)   /* 32 rows per column-chunk */
#define EPSF 1e-8f

typedef unsigned short u16;
typedef __attribute__((ext_vector_type(8))) short bf16x8;
typedef __attribute__((ext_vector_type(4))) float f32x4;

static __device__ __forceinline__ u16 f2bf(float f){
  unsigned int u = __builtin_bit_cast(unsigned int, f);
  u = (u + 0x7FFFu + ((u >> 16) & 1u)) >> 16;
  return (u16)u;
}

// raw barrier: drain LDS ops only; global prefetch stays in flight (no vmcnt drain)
#define BARSYNC() do { \
  asm volatile("s_waitcnt lgkmcnt(0)" ::: "memory"); \
  __builtin_amdgcn_s_barrier(); \
  __builtin_amdgcn_sched_barrier(0); \
} while(0)

// ---------------- reduction helpers (256-thread blocks = 4 waves) ----------------
static __device__ __forceinline__ float wredMax(float v){
#pragma unroll
  for (int o=32;o>=1;o>>=1) v = fmaxf(v, __shfl_xor(v,o,64));
  return v;
}
static __device__ __forceinline__ float wredSum(float v){
#pragma unroll
  for (int o=32;o>=1;o>>=1) v += __shfl_xor(v,o,64);
  return v;
}
static __device__ __forceinline__ float blockMax(float v, float* sm){
  v = wredMax(v);
  int w = threadIdx.x>>6, l = threadIdx.x&63;
  if (l==0) sm[w]=v;
  __syncthreads();
  float r = fmaxf(fmaxf(sm[0],sm[1]),fmaxf(sm[2],sm[3]));
  __syncthreads();
  return r;
}
static __device__ __forceinline__ float blockSum(float v, float* sm){
  v = wredSum(v);
  int w = threadIdx.x>>6, l = threadIdx.x&63;
  if (l==0) sm[w]=v;
  __syncthreads();
  float r = (sm[0]+sm[1])+(sm[2]+sm[3]);
  __syncthreads();
  return r;
}

// ---------------- init: logS/Z as (B,N,D); marginals as small vectors ----------------
__global__ __launch_bounds__(256)
void init_kernel(float* __restrict__ logS, float* __restrict__ Z,
                 const float* __restrict__ p0, const float* __restrict__ q0)
{
  long i = (long)blockIdx.x*256 + threadIdx.x;
  int d  = (int)(i & (D_-1));
  long bn = i >> 9;
  int b  = (int)(bn >> 10);
  logS[i] = logf(q0[bn]*p0[b*D_+d] + EPSF);
  Z[i] = 0.f;
}

// marginal state: M[d]=log_mu, u[d]=z1 d-part, Lv[n]=log_eta, p[n]=z2 n-part
__global__ __launch_bounds__(256)
void margInit_kernel(float* __restrict__ M, float* __restrict__ u,
                     float* __restrict__ Lv, float* __restrict__ p,
                     const float* __restrict__ p0, const float* __restrict__ q0)
{
  int b = blockIdx.x, t = threadIdx.x;
  for (int d = t; d < D_; d += 256){ M[b*D_+d] = logf(p0[b*D_+d]); u[b*D_+d] = 0.f; }
  for (int n = t; n < N_; n += 256){ Lv[b*N_+n] = logf(q0[b*N_+n] + EPSF); p[b*N_+n] = 0.f; }
}

// initX: Xb[b][n][d] = bf16(q0[b][n]*p0[b][d] + eps)  (= exp(logS) row-major for iter 0)
__global__ __launch_bounds__(256)
void initX_kernel(u16* __restrict__ Xb, const float* __restrict__ p0,
                  const float* __restrict__ q0)
{
  long i = (long)blockIdx.x*256 + threadIdx.x;
  int d = (int)(i & (D_-1));
  long bn = i >> 9;
  int b = (int)(bn >> 10);
  Xb[i] = f2bf(p0[b*D_+d]*q0[bn] + EPSF);
}

// ---------------- plain fp32 -> bf16 convert (vectorized x4) ----------------
__global__ __launch_bounds__(256)
void conv_kernel(const float* __restrict__ src, u16* __restrict__ dst)
{
  long i = (long)blockIdx.x*256 + threadIdx.x;
  float4 v = ((const float4*)src)[i];
  ushort4 u;
  u.x=f2bf(v.x); u.y=f2bf(v.y); u.z=f2bf(v.z); u.w=f2bf(v.w);
  ((ushort4*)dst)[i] = u;
}

// ---------------- transpose-convert fp32 [R][C] -> bf16 [C][R], per batch (c1 only) ----------------
__global__ __launch_bounds__(256)
void tconv_kernel(const float* __restrict__ src, u16* __restrict__ dst, int R, int Ccols)
{
  __shared__ float tile[64][65];
  const int b = blockIdx.z;
  const long bb = (long)b*R*Ccols;
  const int r0 = blockIdx.x*64, c0 = blockIdx.y*64;
  const int c = threadIdx.x & 63, rr = threadIdx.x >> 6;
#pragma unroll
  for (int i=0;i<16;i++){
    int r = i*4 + rr;
    tile[r][c] = src[bb + (long)(r0+r)*Ccols + c0 + c];
  }
  __syncthreads();
#pragma unroll
  for (int i=0;i<16;i++){
    int r = i*4 + rr;
    dst[bb + (long)(c0+r)*R + r0 + c] = f2bf(tile[c][r]);
  }
}

// ---------------- bf16 MFMA GEMM, pipelined: C = A[M][K] * Bt[Nc][K]^T, batched ----------------
// 128x64 tile, BK=64, 4 waves (2x2), wave computes 64x32 (acc[4][2]).
// Double-buffered LDS + raw s_barrier (lgkm-only drain): prefetch loads span barriers,
// counted vmcnt waits them at the reg->LDS write (2 steps after issue).
// OUT_TRANS=1: write C^T bf16 (packed ushort4 along the 4-row fragment), ldc = rows of C^T.
template<int K, int OUT_TRANS>
__global__ __launch_bounds__(256)
void gemm_mfma(const u16* __restrict__ Ab, const u16* __restrict__ Btb,
               void* __restrict__ Cp, long sA, long sB, long sC, int ldc)
{
  __shared__ __attribute__((aligned(16))) u16 As[2][128*72];
  __shared__ __attribute__((aligned(16))) u16 Bs[2][64*72];
  const int t = threadIdx.x;
  const int b = blockIdx.z;
  const int row0 = blockIdx.x*128, col0 = blockIdx.y*64;
  const int w = t>>6, l = t&63, lr = l&15, lg = l>>4;
  const int wm = w>>1, wn = w&1;

  f32x4 acc[4][2];
#pragma unroll
  for (int m=0;m<4;m++)
#pragma unroll
    for (int n=0;n<2;n++) acc[m][n] = (f32x4){0.f,0.f,0.f,0.f};

  const u16* Abb = Ab + (long)b*sA + (long)row0*K;
  const u16* Bbb = Btb + (long)b*sB + (long)col0*K;

  bf16x8 a0r[4], b0r[2], a1r[4], b1r[2];

  auto loadA = [&](bf16x8* q, int kk0){
#pragma unroll
    for (int i=0;i<4;i++){ int g=i*256+t; int r=g>>3, j=g&7;
      q[i] = *(const bf16x8*)(Abb + (long)r*K + kk0 + j*8); }
  };
  auto loadB = [&](bf16x8* q, int kk0){
#pragma unroll
    for (int i=0;i<2;i++){ int g=i*256+t; int r=g>>3, j=g&7;
      q[i] = *(const bf16x8*)(Bbb + (long)r*K + kk0 + j*8); }
  };
  auto writeLDS = [&](int buf, const bf16x8* qa, const bf16x8* qb){
#pragma unroll
    for (int i=0;i<4;i++){ int g=i*256+t; int r=g>>3, j=g&7;
      *(bf16x8*)&As[buf][r*72 + j*8] = qa[i]; }
#pragma unroll
    for (int i=0;i<2;i++){ int g=i*256+t; int r=g>>3, j=g&7;
      *(bf16x8*)&Bs[buf][r*72 + j*8] = qb[i]; }
  };
  auto compute = [&](int buf){
#pragma unroll
    for (int kk=0;kk<2;kk++){
      bf16x8 afr[4], bfr[2];
#pragma unroll
      for (int m=0;m<4;m++)
        afr[m] = *(const bf16x8*)&As[buf][(wm*64 + m*16 + lr)*72 + kk*32 + lg*8];
#pragma unroll
      for (int n=0;n<2;n++)
        bfr[n] = *(const bf16x8*)&Bs[buf][(wn*32 + n*16 + lr)*72 + kk*32 + lg*8];
#pragma unroll
      for (int m=0;m<4;m++)
#pragma unroll
        for (int n=0;n<2;n++)
          acc[m][n] = __builtin_amdgcn_mfma_f32_16x16x32_bf16(afr[m], bfr[n], acc[m][n], 0, 0, 0);
    }
  };

  // prologue: tiles 0,1 -> regs; tile 0 -> LDS buf 0
  loadA(a0r, 0); loadB(b0r, 0);
  loadA(a1r, 64); loadB(b1r, 64);
  writeLDS(0, a0r, b0r);             // compiler waits a0r/b0r only (counted vmcnt)

  for (int k0 = 0; k0 < K; k0 += 128) {
    BARSYNC();                       // buf0 ready; a1r/b1r (tile k0+64) in flight
    if (k0+128 < K){ loadA(a0r, k0+128); loadB(b0r, k0+128); }
    compute(0);
    writeLDS(1, a1r, b1r);           // counted vmcnt wait on a1r/b1r
    BARSYNC();                       // buf1 ready; a0r/b0r (tile k0+128) in flight
    if (k0+192 < K){ loadA(a1r, k0+192); loadB(b1r, k0+192); }
    compute(1);
    if (k0+128 < K) writeLDS(0, a0r, b0r);
  }

  // epilogue: D frag mapping col=lane&15, row=(lane>>4)*4+reg  [m89-verified]
  if constexpr (OUT_TRANS) {
    u16* C = (u16*)Cp + (long)b*sC;  // C^T layout [Nc][ldc]
#pragma unroll
    for (int m=0;m<4;m++)
#pragma unroll
      for (int n=0;n<2;n++){
        int grow = row0 + wm*64 + m*16 + lg*4;
        int gcol = col0 + wn*32 + n*16 + lr;
        ushort4 v;
        v.x=f2bf(acc[m][n][0]); v.y=f2bf(acc[m][n][1]);
        v.z=f2bf(acc[m][n][2]); v.w=f2bf(acc[m][n][3]);
        *(ushort4*)&C[(long)gcol*ldc + grow] = v;
      }
  } else {
    float* C = (float*)Cp + (long)b*sC;
#pragma unroll
    for (int m=0;m<4;m++)
#pragma unroll
      for (int n=0;n<2;n++){
        int grow = row0 + wm*64 + m*16 + lg*4;
        int gcol = col0 + wn*32 + n*16 + lr;
#pragma unroll
        for (int r4=0;r4<4;r4++)
          C[(long)(grow+r4)*ldc + gcol] = acc[m][n][r4];
      }
  }
}

// ---------------- row LSE over D: E = exp(M[d] - lse(y) + y); also Xb = bf16(E) row-major ----------------
__global__ __launch_bounds__(256)
void rowA_kernel(const float* __restrict__ x, const float* __restrict__ P2,
                 const float* __restrict__ Z, const float* __restrict__ logS,
                 const float* __restrict__ M, float* __restrict__ E,
                 u16* __restrict__ Xb,
                 const float* __restrict__ a0p, const float* __restrict__ rhop, int it)
{
  __shared__ float sm[4];
  const int bn = blockIdx.x;
  const int b = bn >> 10;
  const long base = (long)bn * D_;
  const float a0 = a0p[it], rho = rhop[it];
  const float inv_rho = 1.f/rho;
  const int d0 = threadIdx.x, d1 = d0 + 256;
  const long i0 = base + d0, i1 = base + d1;
  float y0 = (x[i0] + a0*P2[i0] - Z[i0])*inv_rho + logS[i0];
  float y1 = (x[i1] + a0*P2[i1] - Z[i1])*inv_rho + logS[i1];
  float Mx = blockMax(fmaxf(y0,y1), sm);
  float S = blockSum(expf(y0-Mx)+expf(y1-Mx), sm);
  float lse = Mx + logf(S);
  float e0 = expf(M[b*D_+d0] - lse + y0);
  float e1 = expf(M[b*D_+d1] - lse + y1);
  E[i0] = e0; E[i1] = e1;
  Xb[i0] = f2bf(e0); Xb[i1] = f2bf(e1);
}

// ---------------- col pass 1: y' = (Z + a0*P2 + rho*log(E))/(a1+rho) -> P2; online-LSE partials ----------------
__global__ __launch_bounds__(256)
void colS1_kernel(float* __restrict__ P2, const float* __restrict__ Z,
                  const float* __restrict__ E,
                  float* __restrict__ pMax, float* __restrict__ pSum,
                  const float* __restrict__ a0p, const float* __restrict__ a1p,
                  const float* __restrict__ rhop, int it)
{
  const int d = blockIdx.x*256 + threadIdx.x;
  const int ch = blockIdx.y, b = blockIdx.z;
  const float a0=a0p[it], rho=rhop[it];
  const float inv = 1.f/(a1p[it]+rho);
  long i = (long)b*N_*D_ + (long)(ch*CHUNK)*D_ + d;
  float m = -INFINITY, s = 0.f;
  for (int n=0;n<CHUNK;n++, i+=D_){
    float lt = logf(E[i] + 1e-37f);
    float yv = (Z[i] + a0*P2[i] + rho*lt)*inv;
    P2[i] = yv;
    float mn = fmaxf(m,yv);
    s = s*expf(m-mn) + expf(yv-mn);
    m = mn;
  }
  long pi = ((long)(b*D_+d))*CH + ch;
  pMax[pi]=m; pSum[pi]=s;
}

// ---------------- col pass 2: inline combine; logS, Z update; Xb = bf16(exp(logS)) row-major ----------------
__global__ __launch_bounds__(256)
void colS2_kernel(const float* __restrict__ Yp, const float* __restrict__ E,
                  float* __restrict__ logS, float* __restrict__ Z,
                  const float* __restrict__ Lv,
                  const float* __restrict__ pMax, const float* __restrict__ pSum,
                  const float* __restrict__ maskp, u16* __restrict__ Xb,
                  const float* __restrict__ rhop, int it)
{
  const int tid = threadIdx.x;
  const int d = blockIdx.x*256 + tid;
  const int ch = blockIdx.y, b = blockIdx.z;
  const int n0 = ch*CHUNK;
  const float rho = rhop[it];
  const long bd = (long)(b*D_+d);
  float M = -INFINITY;
#pragma unroll
  for (int c=0;c<CH;c++) M = fmaxf(M, pMax[bd*CH+c]);
  float S = 0.f;
#pragma unroll
  for (int c=0;c<CH;c++) S += pSum[bd*CH+c]*expf(pMax[bd*CH+c]-M);
  const float lseC = M + logf(S);
  long i = (long)b*N_*D_ + (long)n0*D_ + d;
  for (int n=0;n<CHUNK;n++, i+=D_){
    int gn = n0 + n;
    float msk = maskp[b*N_+gn];
    float ls = Lv[b*N_+gn] - lseC + Yp[i];
    logS[i] = ls;
    float es = expf(ls);
    Xb[i] = f2bf(es);
    Z[i] += rho*msk*(E[i] - es);
  }
}

// ---------------- marginal updates (tiny): M/u over D, Lv/p over N ----------------
__global__ __launch_bounds__(256)
void margUpd_kernel(float* __restrict__ M, float* __restrict__ u,
                    float* __restrict__ Lv, float* __restrict__ p,
                    const float* __restrict__ p0, const float* __restrict__ q0,
                    const float* __restrict__ a2p, const float* __restrict__ a3p,
                    const float* __restrict__ rhop, int it)
{
  __shared__ float sm[4];
  const int b = blockIdx.x;
  const float rho = rhop[it];
  if (blockIdx.y == 0) {
    const float a2 = a2p[it], inv = 1.f/(rho+a2);
    const int d0 = threadIdx.x, d1 = d0+256;
    float A0 = (rho*M[b*D_+d0] + a2*logf(p0[b*D_+d0]) - u[b*D_+d0])*inv;
    float A1 = (rho*M[b*D_+d1] + a2*logf(p0[b*D_+d1]) - u[b*D_+d1])*inv;
    float Mx = blockMax(fmaxf(A0,A1), sm);
    float Sx = blockSum(expf(A0-Mx)+expf(A1-Mx), sm);
    float lse = Mx + logf(Sx);
    float M0 = A0 - lse, M1 = A1 - lse;
    M[b*D_+d0]=M0; M[b*D_+d1]=M1;
    u[b*D_+d0] += rho*expf(M0);
    u[b*D_+d1] += rho*expf(M1);
  } else {
    const float a3 = a3p[it], inv = 1.f/(rho+a3);
    const int n = threadIdx.x;
    float y0 = (rho*Lv[b*N_+n]     + a3*logf(q0[b*N_+n]+EPSF)     - p[b*N_+n])*inv;
    float y1 = (rho*Lv[b*N_+n+256] + a3*logf(q0[b*N_+n+256]+EPSF) - p[b*N_+n+256])*inv;
    float y2 = (rho*Lv[b*N_+n+512] + a3*logf(q0[b*N_+n+512]+EPSF) - p[b*N_+n+512])*inv;
    float y3 = (rho*Lv[b*N_+n+768] + a3*logf(q0[b*N_+n+768]+EPSF) - p[b*N_+n+768])*inv;
    float Mx = blockMax(fmaxf(fmaxf(y0,y1),fmaxf(y2,y3)), sm);
    float Sx = blockSum(expf(y0-Mx)+expf(y1-Mx)+expf(y2-Mx)+expf(y3-Mx), sm);
    float lse = Mx + logf(Sx);
    float L0=y0-lse, L1=y1-lse, L2=y2-lse, L3=y3-lse;
    Lv[b*N_+n]=L0; Lv[b*N_+n+256]=L1; Lv[b*N_+n+512]=L2; Lv[b*N_+n+768]=L3;
    p[b*N_+n]     += rho*expf(L0);
    p[b*N_+n+256] += rho*expf(L1);
    p[b*N_+n+512] += rho*expf(L2);
    p[b*N_+n+768] += rho*expf(L3);
  }
}

__global__ __launch_bounds__(256)
void final_kernel(float* __restrict__ E, const float* __restrict__ maskp)
{
  long i = (long)blockIdx.x*256 + threadIdx.x;
  long bn = i >> 9;
  E[i] = E[i]*maskp[bn];
}

// ---------------- launch ----------------
extern "C" void kernel_launch(void* const* d_in, const int* in_sizes, int n_in,
                              void* d_out, int out_size, void* d_ws, size_t ws_size,
                              hipStream_t stream)
{
  const float* x    = (const float*)d_in[0];
  const float* c1   = (const float*)d_in[1];
  const float* c2   = (const float*)d_in[2];
  const float* p0   = (const float*)d_in[3];
  const float* q0   = (const float*)d_in[4];
  const float* a0   = (const float*)d_in[5];
  const float* a1   = (const float*)d_in[6];
  const float* a2   = (const float*)d_in[7];
  const float* a3   = (const float*)d_in[8];
  const float* rho  = (const float*)d_in[9];
  const float* mask = (const float*)d_in[10];

  const size_t BND = (size_t)B_*N_*D_;           // 4,194,304 elements
  char* wb = (char*)d_ws;
  float* logS = (float*)(wb);                    // 3 f32 (B,N,D) buffers
  float* Z    = logS + BND;
  float* P2   = Z    + BND;
  u16*  Xb  = (u16*)(P2 + BND);                  // bf16 [B][N][D] row-major (exp(log·))
  u16*  Yt  = Xb + BND;                          // bf16 [B][D][N]  ((X@c1)^T)
  u16*  c1t = Yt + BND;                          // bf16 [B][D][D]  (c1^T)
  u16*  c2b = c1t + (size_t)B_*D_*D_;            // bf16 [B][N][N]
  float* pMax = (float*)(c2b + (size_t)B_*N_*N_);
  const size_t PART = (size_t)B_*D_*CH;          // 131072
  float* pSum = pMax + PART;
  float* Mv   = pSum + PART;                     // B*D
  float* uv   = Mv + (size_t)B_*D_;              // B*D
  float* Lv   = uv + (size_t)B_*D_;              // B*N
  float* pv   = Lv + (size_t)B_*N_;              // B*N
  float* E    = (float*)d_out;                   // exp(log_t), masked at the end

  dim3 blk(256);
  const int gBND = (int)(BND/256);               // 16384
  dim3 gTc(8, 8, B_);                            // tconv c1: D/64, D/64, B
  dim3 gG(8, 8, B_);                             // gemm: M/128, Nc/64, B -> 512 blocks
  dim3 gCol(D_/256, CH, B_);                     // (2,32,8) -> 512 blocks
  dim3 gMarg(B_, 2);

  const long sC2 = (long)N_*N_, sND = (long)N_*D_, sC1 = (long)D_*D_, sDN = (long)D_*N_;

  init_kernel<<<gBND, blk, 0, stream>>>(logS, Z, p0, q0);
  margInit_kernel<<<B_, blk, 0, stream>>>(Mv, uv, Lv, pv, p0, q0);
  initX_kernel<<<gBND, blk, 0, stream>>>(Xb, p0, q0);
  tconv_kernel<<<gTc, blk, 0, stream>>>(c1, c1t, D_, D_);         // c1t = c1^T bf16
  conv_kernel<<<(int)((size_t)B_*N_*N_/4/256), blk, 0, stream>>>(c2, c2b);

  for (int it=0; it<4; ++it) {
    // ---- log_t update: tmp2 = c2 @ (X @ c1), X = exp(logS) ----
    gemm_mfma< 512,1><<<gG, blk, 0, stream>>>(Xb, c1t, Yt, sND, sC1, sDN, N_);
    gemm_mfma<1024,0><<<gG, blk, 0, stream>>>(c2b, Yt, P2, sC2, sDN, sND, D_);
    rowA_kernel<<<B_*N_, blk, 0, stream>>>(x, P2, Z, logS, Mv, E, Xb, a0, rho, it);
    // ---- log_s update: tmp2 = c2 @ (E @ c1) ----
    gemm_mfma< 512,1><<<gG, blk, 0, stream>>>(Xb, c1t, Yt, sND, sC1, sDN, N_);
    gemm_mfma<1024,0><<<gG, blk, 0, stream>>>(c2b, Yt, P2, sC2, sDN, sND, D_);
    colS1_kernel<<<gCol, blk, 0, stream>>>(P2, Z, E, pMax, pSum, a0, a1, rho, it);
    colS2_kernel<<<gCol, blk, 0, stream>>>(P2, E, logS, Z, Lv, pMax, pSum, mask, Xb, rho, it);
    // ---- marginal updates (small vectors) ----
    margUpd_kernel<<<gMarg, blk, 0, stream>>>(Mv, uv, Lv, pv, p0, q0, a2, a3, rho, it);
  }
  final_kernel<<<gBND, blk, 0, stream>>>(E, mask);
}